// Round 5
// baseline (788.207 us; speedup 1.0000x reference)
//
#include <hip/hip_runtime.h>
#include <cstdint>
#include <cstddef>

typedef _Float16 half_t;
typedef _Float16 half4_t __attribute__((ext_vector_type(4)));
typedef _Float16 half8_t __attribute__((ext_vector_type(8)));
typedef float floatx4 __attribute__((ext_vector_type(4)));

#define NROWS 4096
#define DMODEL 1024
#define NLAT 16384
#define CAND_MAX 256

// ---------------- ws layout (bytes) ----------------
#define MBYTE (1ull << 20)
static const size_t oW0    = 0;                            // 32MB fp16 W_enc*1024
static const size_t oWdT   = 32 * MBYTE;                   // 64MB fp32 W_dec^T
static const size_t oMeanF = 96 * MBYTE;                   // 16KB
static const size_t oNormF = 96 * MBYTE + (64ull << 10);
static const size_t oMeanD = 96 * MBYTE + (128ull << 10);  // 32KB
static const size_t oNormD = 96 * MBYTE + (192ull << 10);  // 32KB
static const size_t oIdx   = 96 * MBYTE + (256ull << 10);  // 512KB
static const size_t oVal   = 96 * MBYTE + (768ull << 10);  // 512KB
static const size_t oCandC = 96 * MBYTE + (1280ull << 10); // 16KB
static const size_t oCandI = 98 * MBYTE;                   // 4096*256*4 = 4MB
static const size_t oCandV = 102 * MBYTE;                  // 4096*256*8 = 8MB
static const size_t oBatch = 110 * MBYTE;

// per-row batch bytes: X0 fp16 (2048) + hb fp16 (32768) + xnbD fp64 (8192)
#define BATCH_ROW_BYTES 43008ull

// ---------------- helpers ----------------
__device__ __forceinline__ void gload16(const void* g, void* l) {
  __builtin_amdgcn_global_load_lds(
      (const __attribute__((address_space(1))) void*)g,
      (__attribute__((address_space(3))) void*)l, 16, 0, 0);
}

__device__ __forceinline__ uint32_t okey(float f) {
  uint32_t u = __float_as_uint(f);
  return (u & 0x80000000u) ? ~u : (u | 0x80000000u);
}

__device__ __forceinline__ float inv_okey(uint32_t k) {
  uint32_t u = (k & 0x80000000u) ? (k & 0x7FFFFFFFu) : ~k;
  return __uint_as_float(u);
}

// ---------------- kernel 1: per-row normalize (fp64 stats) + fp16 pack + fp64 xnb ----------------
__global__ __launch_bounds__(256) void prep_kernel(
    const float* __restrict__ x, const float* __restrict__ b_pre,
    half_t* __restrict__ X0, double* __restrict__ xnbD,
    float* __restrict__ meanF, float* __restrict__ normF,
    double* __restrict__ meanD, double* __restrict__ normD, int r0) {
  int rl = blockIdx.x, tid = threadIdx.x;
  int rg = r0 + rl;
  const float4* px = (const float4*)(x + (size_t)rg * DMODEL);
  float4 v = px[tid];
  double s  = (double)v.x + (double)v.y + (double)v.z + (double)v.w;
  double sq = (double)v.x * v.x + (double)v.y * v.y +
              (double)v.z * v.z + (double)v.w * v.w;
  for (int off = 32; off; off >>= 1) {
    s += __shfl_down(s, off);
    sq += __shfl_down(sq, off);
  }
  __shared__ double ss[4], ssq[4];
  __shared__ double sMean, sNorm;
  int wv = tid >> 6, ln = tid & 63;
  if (ln == 0) { ss[wv] = s; ssq[wv] = sq; }
  __syncthreads();
  if (tid == 0) {
    double S = ss[0] + ss[1] + ss[2] + ss[3];
    double Q = ssq[0] + ssq[1] + ssq[2] + ssq[3];
    double mean = S / (double)DMODEL;
    double var = (Q - (double)DMODEL * mean * mean) / (double)(DMODEL - 1);
    double nrm = sqrt(var) + 1e-6;
    sMean = mean; sNorm = nrm;
    meanF[rg] = (float)mean; normF[rg] = (float)nrm;
    meanD[rg] = mean;        normD[rg] = nrm;
  }
  __syncthreads();
  double meand = sMean, nrmd = sNorm;
  float mean = (float)meand, nrm = (float)nrmd;
  const float4* pb = (const float4*)b_pre;
  float4 bp = pb[tid];
  // fp64 exact normalized row for refinement
  double xd[4];
  xd[0] = ((double)v.x - meand) / nrmd - (double)bp.x;
  xd[1] = ((double)v.y - meand) / nrmd - (double)bp.y;
  xd[2] = ((double)v.z - meand) / nrmd - (double)bp.z;
  xd[3] = ((double)v.w - meand) / nrmd - (double)bp.w;
  double* xp = xnbD + (size_t)rl * DMODEL + tid * 4;
  xp[0] = xd[0]; xp[1] = xd[1]; xp[2] = xd[2]; xp[3] = xd[3];
  // fp16 scaled row for GEMM
  float c[4];
  c[0] = ((v.x - mean) / nrm - bp.x) * 1024.0f;
  c[1] = ((v.y - mean) / nrm - bp.y) * 1024.0f;
  c[2] = ((v.z - mean) / nrm - bp.z) * 1024.0f;
  c[3] = ((v.w - mean) / nrm - bp.w) * 1024.0f;
  half4_t h0;
  for (int i = 0; i < 4; ++i) h0[i] = (half_t)c[i];
  ((half4_t*)(X0 + (size_t)rl * DMODEL))[tid] = h0;
}

// ---------------- kernel 2: W_enc -> fp16 (scaled by 1024) ----------------
__global__ __launch_bounds__(256) void wsplit_kernel(
    const float* __restrict__ W, half_t* __restrict__ W0h) {
  size_t n4 = (size_t)NLAT * DMODEL / 4;
  for (size_t i = (size_t)blockIdx.x * blockDim.x + threadIdx.x; i < n4;
       i += (size_t)gridDim.x * blockDim.x) {
    float4 v = ((const float4*)W)[i];
    half4_t h0;
    h0[0] = (half_t)(v.x * 1024.0f);
    h0[1] = (half_t)(v.y * 1024.0f);
    h0[2] = (half_t)(v.z * 1024.0f);
    h0[3] = (half_t)(v.w * 1024.0f);
    ((half4_t*)W0h)[i] = h0;
  }
}

// ---------------- kernel 3: transpose W_dec [1024][16384] -> [16384][1024] ----------------
__global__ __launch_bounds__(256) void transpose_wdec(
    const float* __restrict__ Wd, float* __restrict__ WdT) {
  __shared__ float tile[64][65];
  int c0 = blockIdx.x * 64;
  int r0 = blockIdx.y * 64;
  int tid = threadIdx.x;
  int tc = tid & 63, tg = tid >> 6;
  for (int i = 0; i < 16; ++i) {
    int rr = i * 4 + tg;
    tile[rr][tc] = Wd[(size_t)(r0 + rr) * NLAT + c0 + tc];
  }
  __syncthreads();
  for (int i = 0; i < 16; ++i) {
    int cc = i * 4 + tg;
    WdT[(size_t)(c0 + cc) * DMODEL + r0 + tc] = tile[tc][cc];
  }
}

// ---------------- kernel 4: encode GEMM (single-pass fp16, K=1024) -> fp16 h ----------------
__global__ __launch_bounds__(256) void gemm_enc(
    const half_t* __restrict__ X0, const half_t* __restrict__ W0,
    const float* __restrict__ b_enc, half_t* __restrict__ h) {
  __shared__ __align__(16) half_t As[128 * 64];
  __shared__ __align__(16) half_t Bs[128 * 64];
  int tid = threadIdx.x;
  int lane = tid & 63, w = tid >> 6;
  int bn = blockIdx.x, bm = blockIdx.y;
  int wr = w >> 1, wc = w & 1;
  floatx4 acc[4][4] = {};

  int ldrow = lane >> 3;
  int ldcol = (lane & 7) * 8;

  for (int kt = 0; kt < 16; ++kt) {
    int kph = kt * 64;
#pragma unroll
    for (int i = 0; i < 4; ++i) {
      int chunk = i * 4 + w;
      int row = chunk * 8 + ldrow;
      gload16(X0 + (size_t)(bm * 128 + row) * DMODEL + kph + ldcol,
              As + chunk * 512);
      gload16(W0 + (size_t)(bn * 128 + row) * DMODEL + kph + ldcol,
              Bs + chunk * 512);
    }
    __syncthreads();
#pragma unroll
    for (int kk = 0; kk < 2; ++kk) {
      half8_t a[4], b[4];
#pragma unroll
      for (int mi = 0; mi < 4; ++mi)
        a[mi] = *(const half8_t*)(As + (wr * 64 + mi * 16 + (lane & 15)) * 64 +
                                  kk * 32 + (lane >> 4) * 8);
#pragma unroll
      for (int ni = 0; ni < 4; ++ni)
        b[ni] = *(const half8_t*)(Bs + (wc * 64 + ni * 16 + (lane & 15)) * 64 +
                                  kk * 32 + (lane >> 4) * 8);
#pragma unroll
      for (int mi = 0; mi < 4; ++mi)
#pragma unroll
        for (int ni = 0; ni < 4; ++ni)
          acc[mi][ni] = __builtin_amdgcn_mfma_f32_16x16x32_f16(
              a[mi], b[ni], acc[mi][ni], 0, 0, 0);
    }
    __syncthreads();
  }

  const float scale = 0x1p-20f;
  int rbase = bm * 128 + wr * 64 + (lane >> 4) * 4;
  int cbase = bn * 128 + wc * 64 + (lane & 15);
#pragma unroll
  for (int mi = 0; mi < 4; ++mi)
#pragma unroll
    for (int ni = 0; ni < 4; ++ni) {
      int col = cbase + ni * 16;
      float be = b_enc[col];
#pragma unroll
      for (int r = 0; r < 4; ++r) {
        int row = rbase + mi * 16 + r;
        h[(size_t)row * NLAT + col] = (half_t)(acc[mi][ni][r] * scale + be);
      }
    }
}

// ---------------- kernel 5: candidate collection (fp16 h, value-space margin) ----------------
__global__ __launch_bounds__(256) void cand_kernel(
    const half_t* __restrict__ h, int* __restrict__ candIdx,
    int* __restrict__ candCnt, int r0) {
  int rl = blockIdx.x, tid = threadIdx.x;
  int rg = r0 + rl;
  const half8_t* ph8 = (const half8_t*)(h + (size_t)rl * NLAT);
  __shared__ uint32_t hist[4096];
  __shared__ int chunkSum[256];
  __shared__ float sThresh;
  __shared__ int cCount;

  for (int i = tid; i < 4096; i += 256) hist[i] = 0;
  if (tid == 0) cCount = 0;
  __syncthreads();

  for (int i = 0; i < 8; ++i) {
    half8_t v = ph8[tid + i * 256];
#pragma unroll
    for (int e = 0; e < 8; ++e) {
      float f = (float)v[e];
      atomicAdd(&hist[okey(f) >> 20], 1u);
    }
  }
  __syncthreads();
  {
    int s = 0;
    for (int b = 0; b < 16; ++b) s += (int)hist[tid * 16 + b];
    chunkSum[tid] = s;
  }
  __syncthreads();
  if (tid == 0) {
    int cum = 0, cchunk = 255;
    for (; cchunk > 0; --cchunk) {
      if (cum + chunkSum[cchunk] >= 32) break;
      cum += chunkSum[cchunk];
    }
    int b = cchunk * 16 + 15;
    for (; b > 0; --b) {
      if (cum + (int)hist[b] >= 32) break;
      cum += (int)hist[b];
    }
    // lower edge of bucket holding approx 32nd value, minus margin
    // (margin 0.05 >> fp16 GEMM noise ~1.3e-3 + fp16 storage ulp ~4e-3)
    sThresh = inv_okey((uint32_t)b << 20) - 0.05f;
  }
  __syncthreads();
  float thresh = sThresh;

  for (int i = 0; i < 8; ++i) {
    half8_t v = ph8[tid + i * 256];
#pragma unroll
    for (int e = 0; e < 8; ++e) {
      float f = (float)v[e];
      if (f >= thresh) {
        int j = (tid + i * 256) * 8 + e;
        int slot = atomicAdd(&cCount, 1);
        if (slot < CAND_MAX) candIdx[(size_t)rg * CAND_MAX + slot] = j;
      }
    }
  }
  __syncthreads();
  if (tid == 0) candCnt[rg] = (cCount < CAND_MAX) ? cCount : CAND_MAX;
}

// ---------------- kernel 6a: fp64 candidate dots (one wave per candidate) ----------------
__global__ __launch_bounds__(256) void refine_dot(
    const double* __restrict__ xnbD, const float* __restrict__ W_enc,
    const float* __restrict__ b_enc,
    const int* __restrict__ candIdx, const int* __restrict__ candCnt,
    double* __restrict__ candV, int r0) {
  int rl = blockIdx.y;
  int rg = r0 + rl;
  int wv = threadIdx.x >> 6, ln = threadIdx.x & 63;
  int c = blockIdx.x * 4 + wv;
  if (c >= candCnt[rg]) return;
  int j = candIdx[(size_t)rg * CAND_MAX + c];
  const float* wr = W_enc + (size_t)j * DMODEL;
  const double* xp = xnbD + (size_t)rl * DMODEL;
  double s = 0.0;
#pragma unroll
  for (int u = 0; u < 16; ++u)
    s += xp[ln + u * 64] * (double)wr[ln + u * 64];
  for (int off = 32; off; off >>= 1) s += __shfl_down(s, off);
  if (ln == 0) candV[(size_t)rg * CAND_MAX + c] = s + (double)b_enc[j];
}

// ---------------- kernel 6b: exact top-32 per row (1 wave) ----------------
__global__ __launch_bounds__(64) void refine_sel(
    const double* __restrict__ candV, const int* __restrict__ candIdx,
    const int* __restrict__ candCnt,
    int* __restrict__ idxOut, float* __restrict__ valOut, int r0) {
  int rg = r0 + blockIdx.x;
  int ln = threadIdx.x;
  __shared__ double cV[CAND_MAX];
  __shared__ int cI[CAND_MAX];
  int nc = candCnt[rg];
  for (int c = ln; c < nc; c += 64) {
    cV[c] = candV[(size_t)rg * CAND_MAX + c];
    cI[c] = candIdx[(size_t)rg * CAND_MAX + c];
  }
  __syncthreads();
  for (int sIt = 0; sIt < 32; ++sIt) {
    double bv = -1.0e300;
    int bi = 0x7FFFFFFF, bc = -1;
    for (int c = ln; c < nc; c += 64) {
      double v = cV[c];
      int ix = cI[c];
      if (v > bv || (v == bv && ix < bi)) { bv = v; bi = ix; bc = c; }
    }
    for (int off = 32; off; off >>= 1) {
      double ov = __shfl_xor(bv, off);
      int oi = __shfl_xor(bi, off);
      int oc = __shfl_xor(bc, off);
      if (ov > bv || (ov == bv && oi < bi)) { bv = ov; bi = oi; bc = oc; }
    }
    if (ln == 0 && bc >= 0) {
      idxOut[(size_t)rg * 32 + sIt] = bi;
      double rv = bv > 0.0 ? bv : 0.0;
      valOut[(size_t)rg * 32 + sIt] = (float)rv;
      cV[bc] = -1.0e300;
    }
    __syncthreads();
  }
}

// ---------------- kernel 7: sparse decode + denormalize ----------------
__global__ __launch_bounds__(256) void decode_kernel(
    const int* __restrict__ idxIn, const float* __restrict__ valIn,
    const float* __restrict__ WdT, const float* __restrict__ b_pre,
    const float* __restrict__ meanF, const float* __restrict__ normF,
    float* __restrict__ out, int r0) {
  int rg = r0 + blockIdx.x, tid = threadIdx.x;
  __shared__ float sVal[32];
  __shared__ int sIdx[32];
  if (tid < 32) {
    sVal[tid] = valIn[(size_t)rg * 32 + tid];
    sIdx[tid] = idxIn[(size_t)rg * 32 + tid];
  }
  __syncthreads();
  int d0 = tid * 4;
  float4 accv = {0.f, 0.f, 0.f, 0.f};
#pragma unroll 8
  for (int k = 0; k < 32; ++k) {
    float vk = sVal[k];
    const float4 wv = *(const float4*)(WdT + (size_t)sIdx[k] * DMODEL + d0);
    accv.x += vk * wv.x; accv.y += vk * wv.y;
    accv.z += vk * wv.z; accv.w += vk * wv.w;
  }
  float4 bp = ((const float4*)b_pre)[tid];
  float nrm = normF[rg], mn = meanF[rg];
  float4 o;
  o.x = (accv.x + bp.x) * nrm + mn;
  o.y = (accv.y + bp.y) * nrm + mn;
  o.z = (accv.z + bp.z) * nrm + mn;
  o.w = (accv.w + bp.w) * nrm + mn;
  ((float4*)(out + (size_t)rg * DMODEL))[tid] = o;
}

// ---------------- launcher ----------------
extern "C" void kernel_launch(void* const* d_in, const int* in_sizes, int n_in,
                              void* d_out, int out_size, void* d_ws, size_t ws_size,
                              hipStream_t stream) {
  const float* x     = (const float*)d_in[0];
  const float* b_pre = (const float*)d_in[1];
  const float* W_enc = (const float*)d_in[2];
  const float* b_enc = (const float*)d_in[3];
  const float* W_dec = (const float*)d_in[4];
  float* out = (float*)d_out;
  char* ws = (char*)d_ws;

  // pick largest row-batch that fits ws_size
  int rowsB = NROWS;
  while (rowsB > 128) {
    size_t need = oBatch + (size_t)rowsB * BATCH_ROW_BYTES;
    if (need <= ws_size) break;
    rowsB >>= 1;
  }
  if (oBatch + (size_t)rowsB * BATCH_ROW_BYTES > ws_size) return;  // fail soft

  half_t* W0 = (half_t*)(ws + oW0);
  float* WdT = (float*)(ws + oWdT);
  float* meanF = (float*)(ws + oMeanF);
  float* normF = (float*)(ws + oNormF);
  double* meanD = (double*)(ws + oMeanD);
  double* normD = (double*)(ws + oNormD);
  int*   idxArr  = (int*)(ws + oIdx);
  float* valArr  = (float*)(ws + oVal);
  int*   candCnt = (int*)(ws + oCandC);
  int*   candIdx = (int*)(ws + oCandI);
  double* candV  = (double*)(ws + oCandV);
  half_t* X0b  = (half_t*)(ws + oBatch);
  half_t* hb   = X0b + (size_t)rowsB * DMODEL;
  double* xnbD = (double*)(hb + (size_t)rowsB * NLAT);

  hipLaunchKernelGGL(wsplit_kernel, dim3(4096), dim3(256), 0, stream, W_enc, W0);
  hipLaunchKernelGGL(transpose_wdec, dim3(NLAT / 64, DMODEL / 64), dim3(256), 0, stream,
                     W_dec, WdT);

  for (int r0 = 0; r0 < NROWS; r0 += rowsB) {
    hipLaunchKernelGGL(prep_kernel, dim3(rowsB), dim3(256), 0, stream,
                       x, b_pre, X0b, xnbD, meanF, normF, meanD, normD, r0);
    hipLaunchKernelGGL(gemm_enc, dim3(NLAT / 128, rowsB / 128), dim3(256), 0, stream,
                       X0b, W0, b_enc, hb);
    hipLaunchKernelGGL(cand_kernel, dim3(rowsB), dim3(256), 0, stream,
                       hb, candIdx, candCnt, r0);
    hipLaunchKernelGGL(refine_dot, dim3(CAND_MAX / 4, rowsB), dim3(256), 0, stream,
                       xnbD, W_enc, b_enc, candIdx, candCnt, candV, r0);
    hipLaunchKernelGGL(refine_sel, dim3(rowsB), dim3(64), 0, stream,
                       candV, candIdx, candCnt, idxArr, valArr, r0);
    hipLaunchKernelGGL(decode_kernel, dim3(rowsB), dim3(256), 0, stream,
                       idxArr, valArr, WdT, b_pre, meanF, normF, out, r0);
  }
}

// Round 6
// 545.052 us; speedup vs baseline: 1.4461x; 1.4461x over previous
//
#include <hip/hip_runtime.h>
#include <cstdint>
#include <cstddef>

typedef _Float16 half_t;
typedef _Float16 half4_t __attribute__((ext_vector_type(4)));
typedef _Float16 half8_t __attribute__((ext_vector_type(8)));
typedef float floatx4 __attribute__((ext_vector_type(4)));

#define NROWS 4096
#define DMODEL 1024
#define NLAT 16384
#define CAND_MAX 256

// ---------------- ws layout (bytes) ----------------
#define MBYTE (1ull << 20)
static const size_t oW0    = 0;                            // 32MB fp16 W_enc*1024
static const size_t oWdT   = 32 * MBYTE;                   // 64MB fp32 W_dec^T
static const size_t oMeanF = 96 * MBYTE;                   // 16KB
static const size_t oNormF = 96 * MBYTE + (64ull << 10);
static const size_t oMeanD = 96 * MBYTE + (128ull << 10);  // 32KB
static const size_t oNormD = 96 * MBYTE + (192ull << 10);  // 32KB
static const size_t oCandC = 96 * MBYTE + (1280ull << 10); // 16KB
static const size_t oCandI = 98 * MBYTE;                   // 4096*256*4 = 4MB
static const size_t oCandV = 102 * MBYTE;                  // 4096*256*8 = 8MB
static const size_t oBatch = 110 * MBYTE;

// per-row batch bytes: X0 fp16 (2048) + hb fp16 (32768) + xnbD fp64 (8192)
#define BATCH_ROW_BYTES 43008ull

// ---------------- helpers ----------------
__device__ __forceinline__ void gload16(const void* g, void* l) {
  __builtin_amdgcn_global_load_lds(
      (const __attribute__((address_space(1))) void*)g,
      (__attribute__((address_space(3))) void*)l, 16, 0, 0);
}

__device__ __forceinline__ uint32_t okey(float f) {
  uint32_t u = __float_as_uint(f);
  return (u & 0x80000000u) ? ~u : (u | 0x80000000u);
}

__device__ __forceinline__ float inv_okey(uint32_t k) {
  uint32_t u = (k & 0x80000000u) ? (k & 0x7FFFFFFFu) : ~k;
  return __uint_as_float(u);
}

// ---------------- kernel 1: per-row normalize (fp64 stats) + fp16 pack + fp64 xnb ----------------
__global__ __launch_bounds__(256) void prep_kernel(
    const float* __restrict__ x, const float* __restrict__ b_pre,
    half_t* __restrict__ X0, double* __restrict__ xnbD,
    float* __restrict__ meanF, float* __restrict__ normF,
    double* __restrict__ meanD, double* __restrict__ normD, int r0) {
  int rl = blockIdx.x, tid = threadIdx.x;
  int rg = r0 + rl;
  const float4* px = (const float4*)(x + (size_t)rg * DMODEL);
  float4 v = px[tid];
  double s  = (double)v.x + (double)v.y + (double)v.z + (double)v.w;
  double sq = (double)v.x * v.x + (double)v.y * v.y +
              (double)v.z * v.z + (double)v.w * v.w;
  for (int off = 32; off; off >>= 1) {
    s += __shfl_down(s, off);
    sq += __shfl_down(sq, off);
  }
  __shared__ double ss[4], ssq[4];
  __shared__ double sMean, sNorm;
  int wv = tid >> 6, ln = tid & 63;
  if (ln == 0) { ss[wv] = s; ssq[wv] = sq; }
  __syncthreads();
  if (tid == 0) {
    double S = ss[0] + ss[1] + ss[2] + ss[3];
    double Q = ssq[0] + ssq[1] + ssq[2] + ssq[3];
    double mean = S / (double)DMODEL;
    double var = (Q - (double)DMODEL * mean * mean) / (double)(DMODEL - 1);
    double nrm = sqrt(var) + 1e-6;
    sMean = mean; sNorm = nrm;
    meanF[rg] = (float)mean; normF[rg] = (float)nrm;
    meanD[rg] = mean;        normD[rg] = nrm;
  }
  __syncthreads();
  double meand = sMean, nrmd = sNorm;
  float mean = (float)meand, nrm = (float)nrmd;
  const float4* pb = (const float4*)b_pre;
  float4 bp = pb[tid];
  // fp64 exact normalized row for refinement
  double xd[4];
  xd[0] = ((double)v.x - meand) / nrmd - (double)bp.x;
  xd[1] = ((double)v.y - meand) / nrmd - (double)bp.y;
  xd[2] = ((double)v.z - meand) / nrmd - (double)bp.z;
  xd[3] = ((double)v.w - meand) / nrmd - (double)bp.w;
  double* xp = xnbD + (size_t)rl * DMODEL + tid * 4;
  xp[0] = xd[0]; xp[1] = xd[1]; xp[2] = xd[2]; xp[3] = xd[3];
  // fp16 scaled row for GEMM
  float c[4];
  c[0] = ((v.x - mean) / nrm - bp.x) * 1024.0f;
  c[1] = ((v.y - mean) / nrm - bp.y) * 1024.0f;
  c[2] = ((v.z - mean) / nrm - bp.z) * 1024.0f;
  c[3] = ((v.w - mean) / nrm - bp.w) * 1024.0f;
  half4_t h0;
  for (int i = 0; i < 4; ++i) h0[i] = (half_t)c[i];
  ((half4_t*)(X0 + (size_t)rl * DMODEL))[tid] = h0;
}

// ---------------- kernel 2: W_enc -> fp16 (scaled by 1024) ----------------
__global__ __launch_bounds__(256) void wsplit_kernel(
    const float* __restrict__ W, half_t* __restrict__ W0h) {
  size_t n4 = (size_t)NLAT * DMODEL / 4;
  for (size_t i = (size_t)blockIdx.x * blockDim.x + threadIdx.x; i < n4;
       i += (size_t)gridDim.x * blockDim.x) {
    float4 v = ((const float4*)W)[i];
    half4_t h0;
    h0[0] = (half_t)(v.x * 1024.0f);
    h0[1] = (half_t)(v.y * 1024.0f);
    h0[2] = (half_t)(v.z * 1024.0f);
    h0[3] = (half_t)(v.w * 1024.0f);
    ((half4_t*)W0h)[i] = h0;
  }
}

// ---------------- kernel 3: transpose W_dec [1024][16384] -> [16384][1024] ----------------
__global__ __launch_bounds__(256) void transpose_wdec(
    const float* __restrict__ Wd, float* __restrict__ WdT) {
  __shared__ float tile[64][65];
  int c0 = blockIdx.x * 64;
  int r0 = blockIdx.y * 64;
  int tid = threadIdx.x;
  int tc = tid & 63, tg = tid >> 6;
  for (int i = 0; i < 16; ++i) {
    int rr = i * 4 + tg;
    tile[rr][tc] = Wd[(size_t)(r0 + rr) * NLAT + c0 + tc];
  }
  __syncthreads();
  for (int i = 0; i < 16; ++i) {
    int cc = i * 4 + tg;
    WdT[(size_t)(c0 + cc) * DMODEL + r0 + tc] = tile[tc][cc];
  }
}

// ---------------- kernel 4: encode GEMM (single-pass fp16, K=1024) -> fp16 h ----------------
__global__ __launch_bounds__(256) void gemm_enc(
    const half_t* __restrict__ X0, const half_t* __restrict__ W0,
    const float* __restrict__ b_enc, half_t* __restrict__ h) {
  __shared__ __align__(16) half_t As[128 * 64];
  __shared__ __align__(16) half_t Bs[128 * 64];
  int tid = threadIdx.x;
  int lane = tid & 63, w = tid >> 6;
  int bn = blockIdx.x, bm = blockIdx.y;
  int wr = w >> 1, wc = w & 1;
  floatx4 acc[4][4] = {};

  int ldrow = lane >> 3;
  int ldcol = (lane & 7) * 8;

  for (int kt = 0; kt < 16; ++kt) {
    int kph = kt * 64;
#pragma unroll
    for (int i = 0; i < 4; ++i) {
      int chunk = i * 4 + w;
      int row = chunk * 8 + ldrow;
      gload16(X0 + (size_t)(bm * 128 + row) * DMODEL + kph + ldcol,
              As + chunk * 512);
      gload16(W0 + (size_t)(bn * 128 + row) * DMODEL + kph + ldcol,
              Bs + chunk * 512);
    }
    __syncthreads();
#pragma unroll
    for (int kk = 0; kk < 2; ++kk) {
      half8_t a[4], b[4];
#pragma unroll
      for (int mi = 0; mi < 4; ++mi)
        a[mi] = *(const half8_t*)(As + (wr * 64 + mi * 16 + (lane & 15)) * 64 +
                                  kk * 32 + (lane >> 4) * 8);
#pragma unroll
      for (int ni = 0; ni < 4; ++ni)
        b[ni] = *(const half8_t*)(Bs + (wc * 64 + ni * 16 + (lane & 15)) * 64 +
                                  kk * 32 + (lane >> 4) * 8);
#pragma unroll
      for (int mi = 0; mi < 4; ++mi)
#pragma unroll
        for (int ni = 0; ni < 4; ++ni)
          acc[mi][ni] = __builtin_amdgcn_mfma_f32_16x16x32_f16(
              a[mi], b[ni], acc[mi][ni], 0, 0, 0);
    }
    __syncthreads();
  }

  const float scale = 0x1p-20f;
  int rbase = bm * 128 + wr * 64 + (lane >> 4) * 4;
  int cbase = bn * 128 + wc * 64 + (lane & 15);
#pragma unroll
  for (int mi = 0; mi < 4; ++mi)
#pragma unroll
    for (int ni = 0; ni < 4; ++ni) {
      int col = cbase + ni * 16;
      float be = b_enc[col];
#pragma unroll
      for (int r = 0; r < 4; ++r) {
        int row = rbase + mi * 16 + r;
        h[(size_t)row * NLAT + col] = (half_t)(acc[mi][ni][r] * scale + be);
      }
    }
}

// ---------------- kernel 5: candidate collection (fp16 h, value-space margin) ----------------
__global__ __launch_bounds__(256) void cand_kernel(
    const half_t* __restrict__ h, int* __restrict__ candIdx,
    int* __restrict__ candCnt, int r0) {
  int rl = blockIdx.x, tid = threadIdx.x;
  int rg = r0 + rl;
  const half8_t* ph8 = (const half8_t*)(h + (size_t)rl * NLAT);
  __shared__ uint32_t hist[4096];
  __shared__ int chunkSum[256];
  __shared__ float sThresh;
  __shared__ int cCount;

  for (int i = tid; i < 4096; i += 256) hist[i] = 0;
  if (tid == 0) cCount = 0;
  __syncthreads();

  for (int i = 0; i < 8; ++i) {
    half8_t v = ph8[tid + i * 256];
#pragma unroll
    for (int e = 0; e < 8; ++e) {
      float f = (float)v[e];
      atomicAdd(&hist[okey(f) >> 20], 1u);
    }
  }
  __syncthreads();
  {
    int s = 0;
    for (int b = 0; b < 16; ++b) s += (int)hist[tid * 16 + b];
    chunkSum[tid] = s;
  }
  __syncthreads();
  if (tid == 0) {
    int cum = 0, cchunk = 255;
    for (; cchunk > 0; --cchunk) {
      if (cum + chunkSum[cchunk] >= 32) break;
      cum += chunkSum[cchunk];
    }
    int b = cchunk * 16 + 15;
    for (; b > 0; --b) {
      if (cum + (int)hist[b] >= 32) break;
      cum += (int)hist[b];
    }
    // lower edge of bucket holding approx 32nd value, minus margin
    // (margin 0.05 >> fp16 GEMM noise ~1.3e-3 + fp16 storage ulp ~4e-3)
    sThresh = inv_okey((uint32_t)b << 20) - 0.05f;
  }
  __syncthreads();
  float thresh = sThresh;

  for (int i = 0; i < 8; ++i) {
    half8_t v = ph8[tid + i * 256];
#pragma unroll
    for (int e = 0; e < 8; ++e) {
      float f = (float)v[e];
      if (f >= thresh) {
        int j = (tid + i * 256) * 8 + e;
        int slot = atomicAdd(&cCount, 1);
        if (slot < CAND_MAX) candIdx[(size_t)rg * CAND_MAX + slot] = j;
      }
    }
  }
  __syncthreads();
  if (tid == 0) candCnt[rg] = (cCount < CAND_MAX) ? cCount : CAND_MAX;
}

// ---------------- kernel 6: fp64 candidate dots, 4-way ILP, x-row in registers ----------------
__global__ __launch_bounds__(256) void refine_dot(
    const double* __restrict__ xnbD, const float* __restrict__ W_enc,
    const float* __restrict__ b_enc,
    const int* __restrict__ candIdx, const int* __restrict__ candCnt,
    double* __restrict__ candV, int r0) {
  int rl = blockIdx.x;
  int rg = r0 + rl;
  int tid = threadIdx.x;
  int wv = tid >> 6, ln = tid & 63;
  const double* xp = xnbD + (size_t)rl * DMODEL;
  double xr[16];
#pragma unroll
  for (int u = 0; u < 16; ++u) xr[u] = xp[ln + u * 64];
  int nc = candCnt[rg];
  const int* ci = candIdx + (size_t)rg * CAND_MAX;

  for (int c0 = wv * 4; c0 < nc; c0 += 16) {
    const float* wp[4];
#pragma unroll
    for (int q = 0; q < 4; ++q) {
      int c = c0 + q;
      int j = ci[c < nc ? c : (nc - 1)];
      wp[q] = W_enc + (size_t)j * DMODEL + ln;
    }
    double a0 = 0.0, a1 = 0.0, a2 = 0.0, a3 = 0.0;
#pragma unroll
    for (int u = 0; u < 16; ++u) {
      float w0 = wp[0][u * 64];
      float w1 = wp[1][u * 64];
      float w2 = wp[2][u * 64];
      float w3 = wp[3][u * 64];
      a0 += xr[u] * (double)w0;
      a1 += xr[u] * (double)w1;
      a2 += xr[u] * (double)w2;
      a3 += xr[u] * (double)w3;
    }
    double accq[4] = {a0, a1, a2, a3};
#pragma unroll
    for (int q = 0; q < 4; ++q) {
      double s = accq[q];
      for (int off = 32; off; off >>= 1) s += __shfl_down(s, off);
      int c = c0 + q;
      if (ln == 0 && c < nc) {
        int j = ci[c];
        candV[(size_t)rg * CAND_MAX + c] = s + (double)b_enc[j];
      }
    }
  }
}

// ---------------- kernel 7: rank-count top-32 select + sparse decode + denormalize ----------------
__global__ __launch_bounds__(256) void sel_decode(
    const double* __restrict__ candV, const int* __restrict__ candIdx,
    const int* __restrict__ candCnt,
    const float* __restrict__ WdT, const float* __restrict__ b_pre,
    const float* __restrict__ meanF, const float* __restrict__ normF,
    float* __restrict__ out, int r0) {
  int rg = r0 + blockIdx.x, tid = threadIdx.x;
  __shared__ double cV[CAND_MAX];
  __shared__ int cI[CAND_MAX];
  __shared__ float sVal[32];
  __shared__ int sIdx[32];
  int nc = candCnt[rg];
  for (int c = tid; c < nc; c += 256) {
    cV[c] = candV[(size_t)rg * CAND_MAX + c];
    cI[c] = candIdx[(size_t)rg * CAND_MAX + c];
  }
  if (tid < 32) { sVal[tid] = 0.0f; sIdx[tid] = 0; }
  __syncthreads();
  // rank-count selection: (value desc, index asc) total order; top-32 have rank<32
  for (int c = tid; c < nc; c += 256) {
    double v = cV[c];
    int ix = cI[c];
    int rank = 0;
    for (int o = 0; o < nc; ++o) {
      double vo = cV[o];
      int io = cI[o];
      rank += (vo > v || (vo == v && io < ix)) ? 1 : 0;
    }
    if (rank < 32) {
      sIdx[rank] = ix;
      sVal[rank] = (float)(v > 0.0 ? v : 0.0);  // relu
    }
  }
  __syncthreads();
  // sparse decode
  int d0 = tid * 4;
  float4 accv = {0.f, 0.f, 0.f, 0.f};
#pragma unroll 8
  for (int k = 0; k < 32; ++k) {
    float vk = sVal[k];
    const float4 wv = *(const float4*)(WdT + (size_t)sIdx[k] * DMODEL + d0);
    accv.x += vk * wv.x; accv.y += vk * wv.y;
    accv.z += vk * wv.z; accv.w += vk * wv.w;
  }
  float4 bp = ((const float4*)b_pre)[tid];
  float nrm = normF[rg], mn = meanF[rg];
  float4 o;
  o.x = (accv.x + bp.x) * nrm + mn;
  o.y = (accv.y + bp.y) * nrm + mn;
  o.z = (accv.z + bp.z) * nrm + mn;
  o.w = (accv.w + bp.w) * nrm + mn;
  ((float4*)(out + (size_t)rg * DMODEL))[tid] = o;
}

// ---------------- launcher ----------------
extern "C" void kernel_launch(void* const* d_in, const int* in_sizes, int n_in,
                              void* d_out, int out_size, void* d_ws, size_t ws_size,
                              hipStream_t stream) {
  const float* x     = (const float*)d_in[0];
  const float* b_pre = (const float*)d_in[1];
  const float* W_enc = (const float*)d_in[2];
  const float* b_enc = (const float*)d_in[3];
  const float* W_dec = (const float*)d_in[4];
  float* out = (float*)d_out;
  char* ws = (char*)d_ws;

  // pick largest row-batch that fits ws_size
  int rowsB = NROWS;
  while (rowsB > 128) {
    size_t need = oBatch + (size_t)rowsB * BATCH_ROW_BYTES;
    if (need <= ws_size) break;
    rowsB >>= 1;
  }
  if (oBatch + (size_t)rowsB * BATCH_ROW_BYTES > ws_size) return;  // fail soft

  half_t* W0 = (half_t*)(ws + oW0);
  float* WdT = (float*)(ws + oWdT);
  float* meanF = (float*)(ws + oMeanF);
  float* normF = (float*)(ws + oNormF);
  double* meanD = (double*)(ws + oMeanD);
  double* normD = (double*)(ws + oNormD);
  int*   candCnt = (int*)(ws + oCandC);
  int*   candIdx = (int*)(ws + oCandI);
  double* candV  = (double*)(ws + oCandV);
  half_t* X0b  = (half_t*)(ws + oBatch);
  half_t* hb   = X0b + (size_t)rowsB * DMODEL;
  double* xnbD = (double*)(hb + (size_t)rowsB * NLAT);

  hipLaunchKernelGGL(wsplit_kernel, dim3(4096), dim3(256), 0, stream, W_enc, W0);
  hipLaunchKernelGGL(transpose_wdec, dim3(NLAT / 64, DMODEL / 64), dim3(256), 0, stream,
                     W_dec, WdT);

  for (int r0 = 0; r0 < NROWS; r0 += rowsB) {
    hipLaunchKernelGGL(prep_kernel, dim3(rowsB), dim3(256), 0, stream,
                       x, b_pre, X0b, xnbD, meanF, normF, meanD, normD, r0);
    hipLaunchKernelGGL(gemm_enc, dim3(NLAT / 128, rowsB / 128), dim3(256), 0, stream,
                       X0b, W0, b_enc, hb);
    hipLaunchKernelGGL(cand_kernel, dim3(rowsB), dim3(256), 0, stream,
                       hb, candIdx, candCnt, r0);
    hipLaunchKernelGGL(refine_dot, dim3(rowsB), dim3(256), 0, stream,
                       xnbD, W_enc, b_enc, candIdx, candCnt, candV, r0);
    hipLaunchKernelGGL(sel_decode, dim3(rowsB), dim3(256), 0, stream,
                       candV, candIdx, candCnt, WdT, b_pre, meanF, normF, out, r0);
  }
}

// Round 7
// 533.185 us; speedup vs baseline: 1.4783x; 1.0223x over previous
//
#include <hip/hip_runtime.h>
#include <cstdint>
#include <cstddef>

typedef _Float16 half_t;
typedef _Float16 half4_t __attribute__((ext_vector_type(4)));
typedef _Float16 half8_t __attribute__((ext_vector_type(8)));
typedef float floatx4 __attribute__((ext_vector_type(4)));

#define NROWS 4096
#define DMODEL 1024
#define NLAT 16384
#define CAND_MAX 256

// ---------------- ws layout (bytes) ----------------
#define MBYTE (1ull << 20)
static const size_t oW0    = 0;                           // 32MB fp16 W_enc*1024
static const size_t oWdT   = 32 * MBYTE;                  // 32MB fp16 W_dec^T
static const size_t oMeanF = 64 * MBYTE;                  // 16KB
static const size_t oNormF = 64 * MBYTE + (64ull << 10);
static const size_t oMeanD = 64 * MBYTE + (128ull << 10); // 32KB
static const size_t oNormD = 64 * MBYTE + (192ull << 10); // 32KB
static const size_t oCandC = 64 * MBYTE + (256ull << 10); // 16KB
static const size_t oCandI = 65 * MBYTE;                  // 4096*256*4 = 4MB
static const size_t oCandV = 69 * MBYTE;                  // 4096*256*8 = 8MB
static const size_t oBatch = 77 * MBYTE;

// per-row batch bytes: X0 fp16 (2048) + hb fp16 (32768)
#define BATCH_ROW_BYTES 34816ull

// ---------------- helpers ----------------
__device__ __forceinline__ void gload16(const void* g, void* l) {
  __builtin_amdgcn_global_load_lds(
      (const __attribute__((address_space(1))) void*)g,
      (__attribute__((address_space(3))) void*)l, 16, 0, 0);
}

__device__ __forceinline__ uint32_t okey(float f) {
  uint32_t u = __float_as_uint(f);
  return (u & 0x80000000u) ? ~u : (u | 0x80000000u);
}

__device__ __forceinline__ float inv_okey(uint32_t k) {
  uint32_t u = (k & 0x80000000u) ? (k & 0x7FFFFFFFu) : ~k;
  return __uint_as_float(u);
}

// ---------------- kernel 1: per-row normalize (fp64 stats) + fp16 pack ----------------
__global__ __launch_bounds__(256) void prep_kernel(
    const float* __restrict__ x, const float* __restrict__ b_pre,
    half_t* __restrict__ X0,
    float* __restrict__ meanF, float* __restrict__ normF,
    double* __restrict__ meanD, double* __restrict__ normD, int r0) {
  int rl = blockIdx.x, tid = threadIdx.x;
  int rg = r0 + rl;
  const float4* px = (const float4*)(x + (size_t)rg * DMODEL);
  float4 v = px[tid];
  double s  = (double)v.x + (double)v.y + (double)v.z + (double)v.w;
  double sq = (double)v.x * v.x + (double)v.y * v.y +
              (double)v.z * v.z + (double)v.w * v.w;
  for (int off = 32; off; off >>= 1) {
    s += __shfl_down(s, off);
    sq += __shfl_down(sq, off);
  }
  __shared__ double ss[4], ssq[4];
  __shared__ double sMean, sNorm;
  int wv = tid >> 6, ln = tid & 63;
  if (ln == 0) { ss[wv] = s; ssq[wv] = sq; }
  __syncthreads();
  if (tid == 0) {
    double S = ss[0] + ss[1] + ss[2] + ss[3];
    double Q = ssq[0] + ssq[1] + ssq[2] + ssq[3];
    double mean = S / (double)DMODEL;
    double var = (Q - (double)DMODEL * mean * mean) / (double)(DMODEL - 1);
    double nrm = sqrt(var) + 1e-6;
    sMean = mean; sNorm = nrm;
    meanF[rg] = (float)mean; normF[rg] = (float)nrm;
    meanD[rg] = mean;        normD[rg] = nrm;
  }
  __syncthreads();
  float mean = (float)sMean, nrm = (float)sNorm;
  const float4* pb = (const float4*)b_pre;
  float4 bp = pb[tid];
  float c[4];
  c[0] = ((v.x - mean) / nrm - bp.x) * 1024.0f;
  c[1] = ((v.y - mean) / nrm - bp.y) * 1024.0f;
  c[2] = ((v.z - mean) / nrm - bp.z) * 1024.0f;
  c[3] = ((v.w - mean) / nrm - bp.w) * 1024.0f;
  half4_t h0;
  for (int i = 0; i < 4; ++i) h0[i] = (half_t)c[i];
  ((half4_t*)(X0 + (size_t)rl * DMODEL))[tid] = h0;
}

// ---------------- kernel 2: W_enc -> fp16 (scaled by 1024) ----------------
__global__ __launch_bounds__(256) void wsplit_kernel(
    const float* __restrict__ W, half_t* __restrict__ W0h) {
  size_t n4 = (size_t)NLAT * DMODEL / 4;
  for (size_t i = (size_t)blockIdx.x * blockDim.x + threadIdx.x; i < n4;
       i += (size_t)gridDim.x * blockDim.x) {
    float4 v = ((const float4*)W)[i];
    half4_t h0;
    h0[0] = (half_t)(v.x * 1024.0f);
    h0[1] = (half_t)(v.y * 1024.0f);
    h0[2] = (half_t)(v.z * 1024.0f);
    h0[3] = (half_t)(v.w * 1024.0f);
    ((half4_t*)W0h)[i] = h0;
  }
}

// ---------------- kernel 3: transpose W_dec [1024][16384] -> fp16 [16384][1024] ----------------
__global__ __launch_bounds__(256) void transpose_wdec(
    const float* __restrict__ Wd, half_t* __restrict__ WdT) {
  __shared__ float tile[64][65];
  int c0 = blockIdx.x * 64;
  int r0 = blockIdx.y * 64;
  int tid = threadIdx.x;
  int tc = tid & 63, tg = tid >> 6;
  for (int i = 0; i < 16; ++i) {
    int rr = i * 4 + tg;
    tile[rr][tc] = Wd[(size_t)(r0 + rr) * NLAT + c0 + tc];
  }
  __syncthreads();
  for (int i = 0; i < 16; ++i) {
    int cc = i * 4 + tg;
    WdT[(size_t)(c0 + cc) * DMODEL + r0 + tc] = (half_t)tile[tc][cc];
  }
}

// ---------------- kernel 4: encode GEMM, 2-phase double-buffered ----------------
__global__ __launch_bounds__(256) void gemm_enc(
    const half_t* __restrict__ X0, const half_t* __restrict__ W0,
    const float* __restrict__ b_enc, half_t* __restrict__ h) {
  __shared__ __align__(16) half_t As[2][128 * 64];
  __shared__ __align__(16) half_t Bs[2][128 * 64];
  int tid = threadIdx.x;
  int lane = tid & 63, w = tid >> 6;
  int bn = blockIdx.x, bm = blockIdx.y;
  int wr = w >> 1, wc = w & 1;
  floatx4 acc[4][4] = {};

  int ldrow = lane >> 3;          // 0..7
  int ldcol = (lane & 7) * 8;     // half units within 64-col K-tile

  const half_t* Abase = X0 + (size_t)(bm * 128) * DMODEL;
  const half_t* Bbase = W0 + (size_t)(bn * 128) * DMODEL;

  // stage K-tile kt into buffer buf (8 x global_load_lds dwordx4 per thread)
#define STAGE(buf, kt)                                                        \
  {                                                                           \
    int kph = (kt) * 64;                                                      \
    _Pragma("unroll") for (int i = 0; i < 4; ++i) {                           \
      int chunk = i * 4 + w;                                                  \
      int row = chunk * 8 + ldrow;                                            \
      gload16(Abase + (size_t)row * DMODEL + kph + ldcol,                     \
              &As[buf][chunk * 512]);                                         \
      gload16(Bbase + (size_t)row * DMODEL + kph + ldcol,                     \
              &Bs[buf][chunk * 512]);                                         \
    }                                                                         \
  }

  STAGE(0, 0);
  __syncthreads();  // drains vmcnt(0): tile 0 resident

  int cur = 0;
  for (int kt = 0; kt < 16; ++kt) {
    if (kt + 1 < 16) STAGE(cur ^ 1, kt + 1);  // prefetch next tile (overlaps MFMA)
#pragma unroll
    for (int kk = 0; kk < 2; ++kk) {
      half8_t a[4], b[4];
#pragma unroll
      for (int mi = 0; mi < 4; ++mi)
        a[mi] = *(const half8_t*)(&As[cur][(wr * 64 + mi * 16 + (lane & 15)) * 64 +
                                           kk * 32 + (lane >> 4) * 8]);
#pragma unroll
      for (int ni = 0; ni < 4; ++ni)
        b[ni] = *(const half8_t*)(&Bs[cur][(wc * 64 + ni * 16 + (lane & 15)) * 64 +
                                           kk * 32 + (lane >> 4) * 8]);
#pragma unroll
      for (int mi = 0; mi < 4; ++mi)
#pragma unroll
        for (int ni = 0; ni < 4; ++ni)
          acc[mi][ni] = __builtin_amdgcn_mfma_f32_16x16x32_f16(
              a[mi], b[ni], acc[mi][ni], 0, 0, 0);
    }
    __syncthreads();  // drains prefetch vmcnt + all reads of cur done
    cur ^= 1;
  }
#undef STAGE

  const float scale = 0x1p-20f;
  int rbase = bm * 128 + wr * 64 + (lane >> 4) * 4;
  int cbase = bn * 128 + wc * 64 + (lane & 15);
#pragma unroll
  for (int mi = 0; mi < 4; ++mi)
#pragma unroll
    for (int ni = 0; ni < 4; ++ni) {
      int col = cbase + ni * 16;
      float be = b_enc[col];
#pragma unroll
      for (int r = 0; r < 4; ++r) {
        int row = rbase + mi * 16 + r;
        h[(size_t)row * NLAT + col] = (half_t)(acc[mi][ni][r] * scale + be);
      }
    }
}

// ---------------- kernel 5: candidate collection, single pass (h row in LDS) ----------------
__global__ __launch_bounds__(256) void cand_kernel(
    const half_t* __restrict__ h, int* __restrict__ candIdx,
    int* __restrict__ candCnt, int r0) {
  int rl = blockIdx.x, tid = threadIdx.x;
  int rg = r0 + rl;
  const half8_t* ph8 = (const half8_t*)(h + (size_t)rl * NLAT);
  __shared__ half_t hrow[NLAT];       // 32KB
  __shared__ uint32_t hist[4096];     // 16KB
  __shared__ int chunkSum[256];
  __shared__ float sThresh;
  __shared__ int cCount;

  for (int i = tid; i < 4096; i += 256) hist[i] = 0;
  if (tid == 0) cCount = 0;
  __syncthreads();

  for (int i = 0; i < 8; ++i) {
    half8_t v = ph8[tid + i * 256];
    ((half8_t*)hrow)[tid + i * 256] = v;
#pragma unroll
    for (int e = 0; e < 8; ++e) {
      float f = (float)v[e];
      atomicAdd(&hist[okey(f) >> 20], 1u);
    }
  }
  __syncthreads();
  {
    int s = 0;
    for (int b = 0; b < 16; ++b) s += (int)hist[tid * 16 + b];
    chunkSum[tid] = s;
  }
  __syncthreads();
  if (tid == 0) {
    int cum = 0, cchunk = 255;
    for (; cchunk > 0; --cchunk) {
      if (cum + chunkSum[cchunk] >= 32) break;
      cum += chunkSum[cchunk];
    }
    int b = cchunk * 16 + 15;
    for (; b > 0; --b) {
      if (cum + (int)hist[b] >= 32) break;
      cum += (int)hist[b];
    }
    // lower edge of bucket holding approx 32nd value, minus margin
    // (margin 0.05 >> fp16 GEMM noise ~1.3e-3 + fp16 storage ulp ~4e-3)
    sThresh = inv_okey((uint32_t)b << 20) - 0.05f;
  }
  __syncthreads();
  float thresh = sThresh;

  for (int i = 0; i < 8; ++i) {
    half8_t v = ((const half8_t*)hrow)[tid + i * 256];
#pragma unroll
    for (int e = 0; e < 8; ++e) {
      float f = (float)v[e];
      if (f >= thresh) {
        int j = (tid + i * 256) * 8 + e;
        int slot = atomicAdd(&cCount, 1);
        if (slot < CAND_MAX) candIdx[(size_t)rg * CAND_MAX + slot] = j;
      }
    }
  }
  __syncthreads();
  if (tid == 0) candCnt[rg] = (cCount < CAND_MAX) ? cCount : CAND_MAX;
}

// ---------------- kernel 6: fp64 candidate dots, 4-way ILP, x-row in registers ----------------
__global__ __launch_bounds__(256) void refine_dot(
    const float* __restrict__ x, const float* __restrict__ b_pre,
    const float* __restrict__ W_enc, const float* __restrict__ b_enc,
    const double* __restrict__ meanD, const double* __restrict__ normD,
    const int* __restrict__ candIdx, const int* __restrict__ candCnt,
    double* __restrict__ candV, int r0) {
  int rg = r0 + blockIdx.x;
  int tid = threadIdx.x;
  int wv = tid >> 6, ln = tid & 63;
  double mean = meanD[rg], nrm = normD[rg];
  const float* px = x + (size_t)rg * DMODEL;
  double xr[16];
#pragma unroll
  for (int u = 0; u < 16; ++u)
    xr[u] = ((double)px[ln + u * 64] - mean) / nrm - (double)b_pre[ln + u * 64];
  int nc = candCnt[rg];
  const int* ci = candIdx + (size_t)rg * CAND_MAX;

  for (int c0 = wv * 4; c0 < nc; c0 += 16) {
    const float* wp[4];
#pragma unroll
    for (int q = 0; q < 4; ++q) {
      int c = c0 + q;
      int j = ci[c < nc ? c : (nc - 1)];
      wp[q] = W_enc + (size_t)j * DMODEL + ln;
    }
    double a0 = 0.0, a1 = 0.0, a2 = 0.0, a3 = 0.0;
#pragma unroll
    for (int u = 0; u < 16; ++u) {
      float w0 = wp[0][u * 64];
      float w1 = wp[1][u * 64];
      float w2 = wp[2][u * 64];
      float w3 = wp[3][u * 64];
      a0 += xr[u] * (double)w0;
      a1 += xr[u] * (double)w1;
      a2 += xr[u] * (double)w2;
      a3 += xr[u] * (double)w3;
    }
    double accq[4] = {a0, a1, a2, a3};
#pragma unroll
    for (int q = 0; q < 4; ++q) {
      double s = accq[q];
      for (int off = 32; off; off >>= 1) s += __shfl_down(s, off);
      int c = c0 + q;
      if (ln == 0 && c < nc) {
        int j = ci[c];
        candV[(size_t)rg * CAND_MAX + c] = s + (double)b_enc[j];
      }
    }
  }
}

// ---------------- kernel 7: rank-count top-32 select + sparse decode (fp16 WdT) ----------------
__global__ __launch_bounds__(256) void sel_decode(
    const double* __restrict__ candV, const int* __restrict__ candIdx,
    const int* __restrict__ candCnt,
    const half_t* __restrict__ WdT, const float* __restrict__ b_pre,
    const float* __restrict__ meanF, const float* __restrict__ normF,
    float* __restrict__ out, int r0) {
  int rg = r0 + blockIdx.x, tid = threadIdx.x;
  __shared__ double cV[CAND_MAX];
  __shared__ int cI[CAND_MAX];
  __shared__ float sVal[32];
  __shared__ int sIdx[32];
  int nc = candCnt[rg];
  for (int c = tid; c < nc; c += 256) {
    cV[c] = candV[(size_t)rg * CAND_MAX + c];
    cI[c] = candIdx[(size_t)rg * CAND_MAX + c];
  }
  if (tid < 32) { sVal[tid] = 0.0f; sIdx[tid] = 0; }
  __syncthreads();
  // rank-count selection: (value desc, index asc) total order; top-32 have rank<32
  for (int c = tid; c < nc; c += 256) {
    double v = cV[c];
    int ix = cI[c];
    int rank = 0;
    for (int o = 0; o < nc; ++o) {
      double vo = cV[o];
      int io = cI[o];
      rank += (vo > v || (vo == v && io < ix)) ? 1 : 0;
    }
    if (rank < 32) {
      sIdx[rank] = ix;
      sVal[rank] = (float)(v > 0.0 ? v : 0.0);  // relu
    }
  }
  __syncthreads();
  // sparse decode
  int d0 = tid * 4;
  float4 accv = {0.f, 0.f, 0.f, 0.f};
#pragma unroll 8
  for (int k = 0; k < 32; ++k) {
    float vk = sVal[k];
    const half4_t wv = *(const half4_t*)(WdT + (size_t)sIdx[k] * DMODEL + d0);
    accv.x += vk * (float)wv[0]; accv.y += vk * (float)wv[1];
    accv.z += vk * (float)wv[2]; accv.w += vk * (float)wv[3];
  }
  float4 bp = ((const float4*)b_pre)[tid];
  float nrm = normF[rg], mn = meanF[rg];
  float4 o;
  o.x = (accv.x + bp.x) * nrm + mn;
  o.y = (accv.y + bp.y) * nrm + mn;
  o.z = (accv.z + bp.z) * nrm + mn;
  o.w = (accv.w + bp.w) * nrm + mn;
  ((float4*)(out + (size_t)rg * DMODEL))[tid] = o;
}

// ---------------- launcher ----------------
extern "C" void kernel_launch(void* const* d_in, const int* in_sizes, int n_in,
                              void* d_out, int out_size, void* d_ws, size_t ws_size,
                              hipStream_t stream) {
  const float* x     = (const float*)d_in[0];
  const float* b_pre = (const float*)d_in[1];
  const float* W_enc = (const float*)d_in[2];
  const float* b_enc = (const float*)d_in[3];
  const float* W_dec = (const float*)d_in[4];
  float* out = (float*)d_out;
  char* ws = (char*)d_ws;

  // pick largest row-batch that fits ws_size
  int rowsB = NROWS;
  while (rowsB > 128) {
    size_t need = oBatch + (size_t)rowsB * BATCH_ROW_BYTES;
    if (need <= ws_size) break;
    rowsB >>= 1;
  }
  if (oBatch + (size_t)rowsB * BATCH_ROW_BYTES > ws_size) return;  // fail soft

  half_t* W0 = (half_t*)(ws + oW0);
  half_t* WdT = (half_t*)(ws + oWdT);
  float* meanF = (float*)(ws + oMeanF);
  float* normF = (float*)(ws + oNormF);
  double* meanD = (double*)(ws + oMeanD);
  double* normD = (double*)(ws + oNormD);
  int*   candCnt = (int*)(ws + oCandC);
  int*   candIdx = (int*)(ws + oCandI);
  double* candV  = (double*)(ws + oCandV);
  half_t* X0b  = (half_t*)(ws + oBatch);
  half_t* hb   = X0b + (size_t)rowsB * DMODEL;

  hipLaunchKernelGGL(wsplit_kernel, dim3(4096), dim3(256), 0, stream, W_enc, W0);
  hipLaunchKernelGGL(transpose_wdec, dim3(NLAT / 64, DMODEL / 64), dim3(256), 0, stream,
                     W_dec, WdT);

  for (int r0 = 0; r0 < NROWS; r0 += rowsB) {
    hipLaunchKernelGGL(prep_kernel, dim3(rowsB), dim3(256), 0, stream,
                       x, b_pre, X0b, meanF, normF, meanD, normD, r0);
    hipLaunchKernelGGL(gemm_enc, dim3(NLAT / 128, rowsB / 128), dim3(256), 0, stream,
                       X0b, W0, b_enc, hb);
    hipLaunchKernelGGL(cand_kernel, dim3(rowsB), dim3(256), 0, stream,
                       hb, candIdx, candCnt, r0);
    hipLaunchKernelGGL(refine_dot, dim3(rowsB), dim3(256), 0, stream,
                       x, b_pre, W_enc, b_enc, meanD, normD, candIdx, candCnt,
                       candV, r0);
    hipLaunchKernelGGL(sel_decode, dim3(rowsB), dim3(256), 0, stream,
                       candV, candIdx, candCnt, WdT, b_pre, meanF, normF, out, r0);
  }
}

// Round 8
// 410.176 us; speedup vs baseline: 1.9216x; 1.2999x over previous
//
#include <hip/hip_runtime.h>
#include <cstdint>
#include <cstddef>

typedef _Float16 half_t;
typedef _Float16 half4_t __attribute__((ext_vector_type(4)));
typedef _Float16 half8_t __attribute__((ext_vector_type(8)));
typedef unsigned short ushort8_t __attribute__((ext_vector_type(8)));
typedef float floatx4 __attribute__((ext_vector_type(4)));

#define NROWS 4096
#define DMODEL 1024
#define NLAT 16384
#define CAND_MAX 256

// ---------------- ws layout (bytes) ----------------
#define MBYTE (1ull << 20)
static const size_t oW0    = 0;                           // 32MB fp16 W_enc*1024
static const size_t oWdT   = 32 * MBYTE;                  // 32MB fp16 W_dec^T
static const size_t oMeanF = 64 * MBYTE;                  // 16KB
static const size_t oNormF = 64 * MBYTE + (64ull << 10);
static const size_t oMeanD = 64 * MBYTE + (128ull << 10); // 32KB
static const size_t oNormD = 64 * MBYTE + (192ull << 10); // 32KB
static const size_t oCandC = 64 * MBYTE + (256ull << 10); // 16KB
static const size_t oCandI = 65 * MBYTE;                  // 4096*256*4 = 4MB
static const size_t oCandV = 69 * MBYTE;                  // 4096*256*8 = 8MB
static const size_t oBatch = 77 * MBYTE;

// per-row batch bytes: X0 fp16 (2048) + hb fp16 (32768)
#define BATCH_ROW_BYTES 34816ull

// ---------------- helpers ----------------
__device__ __forceinline__ void gload16(const void* g, void* l) {
  __builtin_amdgcn_global_load_lds(
      (const __attribute__((address_space(1))) void*)g,
      (__attribute__((address_space(3))) void*)l, 16, 0, 0);
}

// order-preserving key on fp16 bit patterns (13-bit bucket = 8 ulp wide)
__device__ __forceinline__ uint32_t okey16(uint32_t u) {
  return (u & 0x8000u) ? ((~u) & 0xFFFFu) : (u | 0x8000u);
}
__device__ __forceinline__ float inv_okey16(uint32_t k) {
  unsigned short u = (k & 0x8000u) ? (unsigned short)(k & 0x7FFFu)
                                   : (unsigned short)(~k);
  return (float)__builtin_bit_cast(_Float16, u);
}

// ---------------- kernel 1: per-row normalize (fp64 stats) + fp16 pack ----------------
__global__ __launch_bounds__(256) void prep_kernel(
    const float* __restrict__ x, const float* __restrict__ b_pre,
    half_t* __restrict__ X0,
    float* __restrict__ meanF, float* __restrict__ normF,
    double* __restrict__ meanD, double* __restrict__ normD, int r0) {
  int rl = blockIdx.x, tid = threadIdx.x;
  int rg = r0 + rl;
  const float4* px = (const float4*)(x + (size_t)rg * DMODEL);
  float4 v = px[tid];
  double s  = (double)v.x + (double)v.y + (double)v.z + (double)v.w;
  double sq = (double)v.x * v.x + (double)v.y * v.y +
              (double)v.z * v.z + (double)v.w * v.w;
  for (int off = 32; off; off >>= 1) {
    s += __shfl_down(s, off);
    sq += __shfl_down(sq, off);
  }
  __shared__ double ss[4], ssq[4];
  __shared__ double sMean, sNorm;
  int wv = tid >> 6, ln = tid & 63;
  if (ln == 0) { ss[wv] = s; ssq[wv] = sq; }
  __syncthreads();
  if (tid == 0) {
    double S = ss[0] + ss[1] + ss[2] + ss[3];
    double Q = ssq[0] + ssq[1] + ssq[2] + ssq[3];
    double mean = S / (double)DMODEL;
    double var = (Q - (double)DMODEL * mean * mean) / (double)(DMODEL - 1);
    double nrm = sqrt(var) + 1e-6;
    sMean = mean; sNorm = nrm;
    meanF[rg] = (float)mean; normF[rg] = (float)nrm;
    meanD[rg] = mean;        normD[rg] = nrm;
  }
  __syncthreads();
  float mean = (float)sMean, nrm = (float)sNorm;
  const float4* pb = (const float4*)b_pre;
  float4 bp = pb[tid];
  float c[4];
  c[0] = ((v.x - mean) / nrm - bp.x) * 1024.0f;
  c[1] = ((v.y - mean) / nrm - bp.y) * 1024.0f;
  c[2] = ((v.z - mean) / nrm - bp.z) * 1024.0f;
  c[3] = ((v.w - mean) / nrm - bp.w) * 1024.0f;
  half4_t h0;
  for (int i = 0; i < 4; ++i) h0[i] = (half_t)c[i];
  ((half4_t*)(X0 + (size_t)rl * DMODEL))[tid] = h0;
}

// ---------------- kernel 2: W_enc -> fp16 (scaled by 1024) ----------------
__global__ __launch_bounds__(256) void wsplit_kernel(
    const float* __restrict__ W, half_t* __restrict__ W0h) {
  size_t n4 = (size_t)NLAT * DMODEL / 4;
  for (size_t i = (size_t)blockIdx.x * blockDim.x + threadIdx.x; i < n4;
       i += (size_t)gridDim.x * blockDim.x) {
    float4 v = ((const float4*)W)[i];
    half4_t h0;
    h0[0] = (half_t)(v.x * 1024.0f);
    h0[1] = (half_t)(v.y * 1024.0f);
    h0[2] = (half_t)(v.z * 1024.0f);
    h0[3] = (half_t)(v.w * 1024.0f);
    ((half4_t*)W0h)[i] = h0;
  }
}

// ---------------- kernel 3: transpose W_dec [1024][16384] -> fp16 [16384][1024] ----------------
__global__ __launch_bounds__(256) void transpose_wdec(
    const float* __restrict__ Wd, half_t* __restrict__ WdT) {
  __shared__ float tile[64][65];
  int c0 = blockIdx.x * 64;
  int r0 = blockIdx.y * 64;
  int tid = threadIdx.x;
  int tc = tid & 63, tg = tid >> 6;
  for (int i = 0; i < 16; ++i) {
    int rr = i * 4 + tg;
    tile[rr][tc] = Wd[(size_t)(r0 + rr) * NLAT + c0 + tc];
  }
  __syncthreads();
  for (int i = 0; i < 16; ++i) {
    int cc = i * 4 + tg;
    WdT[(size_t)(c0 + cc) * DMODEL + r0 + tc] = (half_t)tile[tc][cc];
  }
}

// ---------------- kernel 4: encode GEMM (single-buffer m97 structure + XCD swizzle) ----------------
__global__ __launch_bounds__(256, 3) void gemm_enc(
    const half_t* __restrict__ X0, const half_t* __restrict__ W0,
    const float* __restrict__ b_enc, half_t* __restrict__ h) {
  __shared__ __align__(16) half_t As[128 * 64];
  __shared__ __align__(16) half_t Bs[128 * 64];
  int tid = threadIdx.x;
  int lane = tid & 63, w = tid >> 6;
  // XCD-aware swizzle of the linear block id: blocks sharing a B-panel
  // (stride gridDim.x in linear order, 128%8==0) land on the same XCD chunk.
  int lin = blockIdx.y * gridDim.x + blockIdx.x;
  int nwg = gridDim.x * gridDim.y;           // multiple of 8
  int cpx = nwg >> 3;
  int swz = (lin & 7) * cpx + (lin >> 3);
  int bm = swz >> 7;                          // / 128
  int bn = swz & 127;
  int wr = w >> 1, wc = w & 1;
  floatx4 acc[4][4] = {};

  int ldrow = lane >> 3;
  int ldcol = (lane & 7) * 8;

  for (int kt = 0; kt < 16; ++kt) {
    int kph = kt * 64;
#pragma unroll
    for (int i = 0; i < 4; ++i) {
      int chunk = i * 4 + w;
      int row = chunk * 8 + ldrow;
      gload16(X0 + (size_t)(bm * 128 + row) * DMODEL + kph + ldcol,
              As + chunk * 512);
      gload16(W0 + (size_t)(bn * 128 + row) * DMODEL + kph + ldcol,
              Bs + chunk * 512);
    }
    __syncthreads();
#pragma unroll
    for (int kk = 0; kk < 2; ++kk) {
      half8_t a[4], b[4];
#pragma unroll
      for (int mi = 0; mi < 4; ++mi)
        a[mi] = *(const half8_t*)(As + (wr * 64 + mi * 16 + (lane & 15)) * 64 +
                                  kk * 32 + (lane >> 4) * 8);
#pragma unroll
      for (int ni = 0; ni < 4; ++ni)
        b[ni] = *(const half8_t*)(Bs + (wc * 64 + ni * 16 + (lane & 15)) * 64 +
                                  kk * 32 + (lane >> 4) * 8);
#pragma unroll
      for (int mi = 0; mi < 4; ++mi)
#pragma unroll
        for (int ni = 0; ni < 4; ++ni)
          acc[mi][ni] = __builtin_amdgcn_mfma_f32_16x16x32_f16(
              a[mi], b[ni], acc[mi][ni], 0, 0, 0);
    }
    __syncthreads();
  }

  const float scale = 0x1p-20f;
  int rbase = bm * 128 + wr * 64 + (lane >> 4) * 4;
  int cbase = bn * 128 + wc * 64 + (lane & 15);
#pragma unroll
  for (int mi = 0; mi < 4; ++mi)
#pragma unroll
    for (int ni = 0; ni < 4; ++ni) {
      int col = cbase + ni * 16;
      float be = b_enc[col];
#pragma unroll
      for (int r = 0; r < 4; ++r) {
        int row = rbase + mi * 16 + r;
        h[(size_t)row * NLAT + col] = (half_t)(acc[mi][ni][r] * scale + be);
      }
    }
}

// ---------------- kernel 5: candidate collection (13-bit fp16-key histogram) ----------------
__global__ __launch_bounds__(256) void cand_kernel(
    const half_t* __restrict__ h, int* __restrict__ candIdx,
    int* __restrict__ candCnt, int r0) {
  int rl = blockIdx.x, tid = threadIdx.x;
  int rg = r0 + rl;
  const ushort8_t* ph8 = (const ushort8_t*)(h + (size_t)rl * NLAT);
  __shared__ uint32_t hist[8192];   // 32KB, bucket = 8 fp16-ulp
  __shared__ int chunkSum[256];
  __shared__ float sThresh;
  __shared__ int cCount;

  for (int i = tid; i < 8192; i += 256) hist[i] = 0;
  if (tid == 0) cCount = 0;
  __syncthreads();

  for (int i = 0; i < 8; ++i) {
    ushort8_t v = ph8[tid + i * 256];
#pragma unroll
    for (int e = 0; e < 8; ++e)
      atomicAdd(&hist[okey16((uint32_t)v[e]) >> 3], 1u);
  }
  __syncthreads();
  {
    int s = 0;
    for (int b = 0; b < 32; ++b) s += (int)hist[tid * 32 + b];
    chunkSum[tid] = s;
  }
  __syncthreads();
  if (tid == 0) {
    int cum = 0, cchunk = 255;
    for (; cchunk > 0; --cchunk) {
      if (cum + chunkSum[cchunk] >= 32) break;
      cum += chunkSum[cchunk];
    }
    int b = cchunk * 32 + 31;
    for (; b > 0; --b) {
      if (cum + (int)hist[b] >= 32) break;
      cum += (int)hist[b];
    }
    // bucket lower edge minus margin; margin 0.02 >= 2*(fp16 GEMM noise
    // ~5e-3 + fp16 storage rounding ~1e-3) at far tail
    sThresh = inv_okey16((uint32_t)b << 3) - 0.02f;
  }
  __syncthreads();
  float thresh = sThresh;

  for (int i = 0; i < 8; ++i) {
    ushort8_t v = ph8[tid + i * 256];
#pragma unroll
    for (int e = 0; e < 8; ++e) {
      float f = (float)__builtin_bit_cast(_Float16, (unsigned short)v[e]);
      if (f >= thresh) {
        int j = (tid + i * 256) * 8 + e;
        int slot = atomicAdd(&cCount, 1);
        if (slot < CAND_MAX) candIdx[(size_t)rg * CAND_MAX + slot] = j;
      }
    }
  }
  __syncthreads();
  if (tid == 0) candCnt[rg] = (cCount < CAND_MAX) ? cCount : CAND_MAX;
}

// ---------------- kernel 6: fp64 candidate dots, 4-way ILP, x-row in registers ----------------
__global__ __launch_bounds__(256) void refine_dot(
    const float* __restrict__ x, const float* __restrict__ b_pre,
    const float* __restrict__ W_enc, const float* __restrict__ b_enc,
    const double* __restrict__ meanD, const double* __restrict__ normD,
    const int* __restrict__ candIdx, const int* __restrict__ candCnt,
    double* __restrict__ candV, int r0) {
  int rg = r0 + blockIdx.x;
  int tid = threadIdx.x;
  int wv = tid >> 6, ln = tid & 63;
  double mean = meanD[rg], nrm = normD[rg];
  const float* px = x + (size_t)rg * DMODEL;
  double xr[16];
#pragma unroll
  for (int u = 0; u < 16; ++u)
    xr[u] = ((double)px[ln + u * 64] - mean) / nrm - (double)b_pre[ln + u * 64];
  int nc = candCnt[rg];
  const int* ci = candIdx + (size_t)rg * CAND_MAX;

  for (int c0 = wv * 4; c0 < nc; c0 += 16) {
    const float* wp[4];
#pragma unroll
    for (int q = 0; q < 4; ++q) {
      int c = c0 + q;
      int j = ci[c < nc ? c : (nc - 1)];
      wp[q] = W_enc + (size_t)j * DMODEL + ln;
    }
    double a0 = 0.0, a1 = 0.0, a2 = 0.0, a3 = 0.0;
#pragma unroll
    for (int u = 0; u < 16; ++u) {
      float w0 = wp[0][u * 64];
      float w1 = wp[1][u * 64];
      float w2 = wp[2][u * 64];
      float w3 = wp[3][u * 64];
      a0 += xr[u] * (double)w0;
      a1 += xr[u] * (double)w1;
      a2 += xr[u] * (double)w2;
      a3 += xr[u] * (double)w3;
    }
    double accq[4] = {a0, a1, a2, a3};
#pragma unroll
    for (int q = 0; q < 4; ++q) {
      double s = accq[q];
      for (int off = 32; off; off >>= 1) s += __shfl_down(s, off);
      int c = c0 + q;
      if (ln == 0 && c < nc) {
        int j = ci[c];
        candV[(size_t)rg * CAND_MAX + c] = s + (double)b_enc[j];
      }
    }
  }
}

// ---------------- kernel 7: rank-count top-32 select + sparse decode (fp16 WdT) ----------------
__global__ __launch_bounds__(256) void sel_decode(
    const double* __restrict__ candV, const int* __restrict__ candIdx,
    const int* __restrict__ candCnt,
    const half_t* __restrict__ WdT, const float* __restrict__ b_pre,
    const float* __restrict__ meanF, const float* __restrict__ normF,
    float* __restrict__ out, int r0) {
  int rg = r0 + blockIdx.x, tid = threadIdx.x;
  __shared__ double cV[CAND_MAX];
  __shared__ int cI[CAND_MAX];
  __shared__ float sVal[32];
  __shared__ int sIdx[32];
  int nc = candCnt[rg];
  for (int c = tid; c < nc; c += 256) {
    cV[c] = candV[(size_t)rg * CAND_MAX + c];
    cI[c] = candIdx[(size_t)rg * CAND_MAX + c];
  }
  if (tid < 32) { sVal[tid] = 0.0f; sIdx[tid] = 0; }
  __syncthreads();
  // rank-count selection: (value desc, index asc) total order; top-32 have rank<32
  for (int c = tid; c < nc; c += 256) {
    double v = cV[c];
    int ix = cI[c];
    int rank = 0;
    for (int o = 0; o < nc; ++o) {
      double vo = cV[o];
      int io = cI[o];
      rank += (vo > v || (vo == v && io < ix)) ? 1 : 0;
    }
    if (rank < 32) {
      sIdx[rank] = ix;
      sVal[rank] = (float)(v > 0.0 ? v : 0.0);  // relu
    }
  }
  __syncthreads();
  // sparse decode
  int d0 = tid * 4;
  float4 accv = {0.f, 0.f, 0.f, 0.f};
#pragma unroll 8
  for (int k = 0; k < 32; ++k) {
    float vk = sVal[k];
    const half4_t wv = *(const half4_t*)(WdT + (size_t)sIdx[k] * DMODEL + d0);
    accv.x += vk * (float)wv[0]; accv.y += vk * (float)wv[1];
    accv.z += vk * (float)wv[2]; accv.w += vk * (float)wv[3];
  }
  float4 bp = ((const float4*)b_pre)[tid];
  float nrm = normF[rg], mn = meanF[rg];
  float4 o;
  o.x = (accv.x + bp.x) * nrm + mn;
  o.y = (accv.y + bp.y) * nrm + mn;
  o.z = (accv.z + bp.z) * nrm + mn;
  o.w = (accv.w + bp.w) * nrm + mn;
  ((float4*)(out + (size_t)rg * DMODEL))[tid] = o;
}

// ---------------- launcher ----------------
extern "C" void kernel_launch(void* const* d_in, const int* in_sizes, int n_in,
                              void* d_out, int out_size, void* d_ws, size_t ws_size,
                              hipStream_t stream) {
  const float* x     = (const float*)d_in[0];
  const float* b_pre = (const float*)d_in[1];
  const float* W_enc = (const float*)d_in[2];
  const float* b_enc = (const float*)d_in[3];
  const float* W_dec = (const float*)d_in[4];
  float* out = (float*)d_out;
  char* ws = (char*)d_ws;

  // pick largest row-batch that fits ws_size
  int rowsB = NROWS;
  while (rowsB > 128) {
    size_t need = oBatch + (size_t)rowsB * BATCH_ROW_BYTES;
    if (need <= ws_size) break;
    rowsB >>= 1;
  }
  if (oBatch + (size_t)rowsB * BATCH_ROW_BYTES > ws_size) return;  // fail soft

  half_t* W0 = (half_t*)(ws + oW0);
  half_t* WdT = (half_t*)(ws + oWdT);
  float* meanF = (float*)(ws + oMeanF);
  float* normF = (float*)(ws + oNormF);
  double* meanD = (double*)(ws + oMeanD);
  double* normD = (double*)(ws + oNormD);
  int*   candCnt = (int*)(ws + oCandC);
  int*   candIdx = (int*)(ws + oCandI);
  double* candV  = (double*)(ws + oCandV);
  half_t* X0b  = (half_t*)(ws + oBatch);
  half_t* hb   = X0b + (size_t)rowsB * DMODEL;

  hipLaunchKernelGGL(wsplit_kernel, dim3(4096), dim3(256), 0, stream, W_enc, W0);
  hipLaunchKernelGGL(transpose_wdec, dim3(NLAT / 64, DMODEL / 64), dim3(256), 0, stream,
                     W_dec, WdT);

  for (int r0 = 0; r0 < NROWS; r0 += rowsB) {
    hipLaunchKernelGGL(prep_kernel, dim3(rowsB), dim3(256), 0, stream,
                       x, b_pre, X0b, meanF, normF, meanD, normD, r0);
    hipLaunchKernelGGL(gemm_enc, dim3(NLAT / 128, rowsB / 128), dim3(256), 0, stream,
                       X0b, W0, b_enc, hb);
    hipLaunchKernelGGL(cand_kernel, dim3(rowsB), dim3(256), 0, stream,
                       hb, candIdx, candCnt, r0);
    hipLaunchKernelGGL(refine_dot, dim3(rowsB), dim3(256), 0, stream,
                       x, b_pre, W_enc, b_enc, meanD, normD, candIdx, candCnt,
                       candV, r0);
    hipLaunchKernelGGL(sel_decode, dim3(rowsB), dim3(256), 0, stream,
                       candV, candIdx, candCnt, WdT, b_pre, meanF, normF, out, r0);
  }
}

// Round 9
// 383.292 us; speedup vs baseline: 2.0564x; 1.0701x over previous
//
#include <hip/hip_runtime.h>
#include <cstdint>
#include <cstddef>

typedef _Float16 half_t;
typedef _Float16 half4_t __attribute__((ext_vector_type(4)));
typedef _Float16 half8_t __attribute__((ext_vector_type(8)));
typedef unsigned short ushort8_t __attribute__((ext_vector_type(8)));
typedef float floatx4 __attribute__((ext_vector_type(4)));

#define NROWS 4096
#define DMODEL 1024
#define NLAT 16384
#define CAND_MAX 256

// ---------------- ws layout (bytes) ----------------
#define MBYTE (1ull << 20)
static const size_t oW0    = 0;                           // 32MB fp16 W_enc*1024
static const size_t oWdT   = 32 * MBYTE;                  // 32MB fp16 W_dec^T
static const size_t oMeanF = 64 * MBYTE;                  // 16KB
static const size_t oNormF = 64 * MBYTE + (64ull << 10);
static const size_t oMeanD = 64 * MBYTE + (128ull << 10); // 32KB
static const size_t oNormD = 64 * MBYTE + (192ull << 10); // 32KB
static const size_t oCandC = 64 * MBYTE + (256ull << 10); // 16KB
static const size_t oCandI = 65 * MBYTE;                  // 4096*256*4 = 4MB
static const size_t oCandV = 69 * MBYTE;                  // 4096*256*8 = 8MB
static const size_t oBatch = 77 * MBYTE;

// per-row batch bytes: X0 fp16 (2048) + hb fp16 (32768)
#define BATCH_ROW_BYTES 34816ull

// ---------------- helpers ----------------
__device__ __forceinline__ void gload16(const void* g, void* l) {
  __builtin_amdgcn_global_load_lds(
      (const __attribute__((address_space(1))) void*)g,
      (__attribute__((address_space(3))) void*)l, 16, 0, 0);
}

// order-preserving key on fp16 bit patterns (13-bit bucket = 8 ulp wide)
__device__ __forceinline__ uint32_t okey16(uint32_t u) {
  return (u & 0x8000u) ? ((~u) & 0xFFFFu) : (u | 0x8000u);
}
__device__ __forceinline__ float inv_okey16(uint32_t k) {
  unsigned short u = (k & 0x8000u) ? (unsigned short)(k & 0x7FFFu)
                                   : (unsigned short)(~k);
  return (float)__builtin_bit_cast(_Float16, u);
}

// ---------------- kernel 1: fused preprocessing ----------------
// blocks [0, WSPLIT_B):                 W_enc -> fp16*1024
// blocks [WSPLIT_B, WSPLIT_B+TRANS_B):  W_dec transpose -> fp16 [16384][1024]
// blocks [WSPLIT_B+TRANS_B, +rowsB):    per-row normalize + fp16 pack
#define WSPLIT_B 2048
#define TRANS_B  4096   // (NLAT/64) * (DMODEL/64)
__global__ __launch_bounds__(256) void prepro_kernel(
    const float* __restrict__ x, const float* __restrict__ b_pre,
    const float* __restrict__ W_enc, const float* __restrict__ Wd,
    half_t* __restrict__ W0h, half_t* __restrict__ WdT,
    half_t* __restrict__ X0,
    float* __restrict__ meanF, float* __restrict__ normF,
    double* __restrict__ meanD, double* __restrict__ normD, int r0) {
  int bid = blockIdx.x, tid = threadIdx.x;
  if (bid < WSPLIT_B) {
    // ---- W_enc split: 4M float4 over 2048 blocks = 8 per thread
    size_t base = (size_t)bid * 2048 + tid;
    for (int it = 0; it < 8; ++it) {
      size_t i = base + (size_t)it * 256;
      float4 v = ((const float4*)W_enc)[i];
      half4_t h0;
      h0[0] = (half_t)(v.x * 1024.0f);
      h0[1] = (half_t)(v.y * 1024.0f);
      h0[2] = (half_t)(v.z * 1024.0f);
      h0[3] = (half_t)(v.w * 1024.0f);
      ((half4_t*)W0h)[i] = h0;
    }
    return;
  }
  if (bid < WSPLIT_B + TRANS_B) {
    // ---- W_dec transpose tile
    __shared__ float tile[64][65];
    int t = bid - WSPLIT_B;
    int c0 = (t & 255) * 64;   // over NLAT
    int r0t = (t >> 8) * 64;   // over DMODEL
    int tc = tid & 63, tg = tid >> 6;
    for (int i = 0; i < 16; ++i) {
      int rr = i * 4 + tg;
      tile[rr][tc] = Wd[(size_t)(r0t + rr) * NLAT + c0 + tc];
    }
    __syncthreads();
    for (int i = 0; i < 16; ++i) {
      int cc = i * 4 + tg;
      WdT[(size_t)(c0 + cc) * DMODEL + r0t + tc] = (half_t)tile[tc][cc];
    }
    return;
  }
  // ---- per-row normalize
  int rl = bid - WSPLIT_B - TRANS_B;
  int rg = r0 + rl;
  const float4* px = (const float4*)(x + (size_t)rg * DMODEL);
  float4 v = px[tid];
  double s  = (double)v.x + (double)v.y + (double)v.z + (double)v.w;
  double sq = (double)v.x * v.x + (double)v.y * v.y +
              (double)v.z * v.z + (double)v.w * v.w;
  for (int off = 32; off; off >>= 1) {
    s += __shfl_down(s, off);
    sq += __shfl_down(sq, off);
  }
  __shared__ double ss[4], ssq[4];
  __shared__ double sMean, sNorm;
  int wv = tid >> 6, ln = tid & 63;
  if (ln == 0) { ss[wv] = s; ssq[wv] = sq; }
  __syncthreads();
  if (tid == 0) {
    double S = ss[0] + ss[1] + ss[2] + ss[3];
    double Q = ssq[0] + ssq[1] + ssq[2] + ssq[3];
    double mean = S / (double)DMODEL;
    double var = (Q - (double)DMODEL * mean * mean) / (double)(DMODEL - 1);
    double nrm = sqrt(var) + 1e-6;
    sMean = mean; sNorm = nrm;
    meanF[rg] = (float)mean; normF[rg] = (float)nrm;
    meanD[rg] = mean;        normD[rg] = nrm;
  }
  __syncthreads();
  float mean = (float)sMean, nrm = (float)sNorm;
  const float4* pb = (const float4*)b_pre;
  float4 bp = pb[tid];
  float c[4];
  c[0] = ((v.x - mean) / nrm - bp.x) * 1024.0f;
  c[1] = ((v.y - mean) / nrm - bp.y) * 1024.0f;
  c[2] = ((v.z - mean) / nrm - bp.z) * 1024.0f;
  c[3] = ((v.w - mean) / nrm - bp.w) * 1024.0f;
  half4_t h0;
  for (int i = 0; i < 4; ++i) h0[i] = (half_t)c[i];
  ((half4_t*)(X0 + (size_t)rl * DMODEL))[tid] = h0;
}

// ---------------- kernel 2: encode GEMM (m97 structure + bn-chunk XCD swizzle) ----------------
__global__ __launch_bounds__(256, 4) void gemm_enc(
    const half_t* __restrict__ X0, const half_t* __restrict__ W0,
    const float* __restrict__ b_enc, half_t* __restrict__ h) {
  __shared__ __align__(16) half_t As[128 * 64];
  __shared__ __align__(16) half_t Bs[128 * 64];
  int tid = threadIdx.x;
  int lane = tid & 63, w = tid >> 6;
  // XCD-ownership swizzle: XCD x owns bn in [x*16,(x+1)*16) (4MB of W0 ->
  // L2-resident) and streams bm; A (8MB total) is L3-shared across XCDs.
  int lin = blockIdx.y * gridDim.x + blockIdx.x;
  int xcd = lin & 7;
  int q = lin >> 3;
  int bn = xcd * 16 + (q & 15);
  int bm = q >> 4;
  int wr = w >> 1, wc = w & 1;
  floatx4 acc[4][4] = {};

  int ldrow = lane >> 3;
  int ldcol = (lane & 7) * 8;

  for (int kt = 0; kt < 16; ++kt) {
    int kph = kt * 64;
#pragma unroll
    for (int i = 0; i < 4; ++i) {
      int chunk = i * 4 + w;
      int row = chunk * 8 + ldrow;
      gload16(X0 + (size_t)(bm * 128 + row) * DMODEL + kph + ldcol,
              As + chunk * 512);
      gload16(W0 + (size_t)(bn * 128 + row) * DMODEL + kph + ldcol,
              Bs + chunk * 512);
    }
    __syncthreads();
#pragma unroll
    for (int kk = 0; kk < 2; ++kk) {
      half8_t a[4], b[4];
#pragma unroll
      for (int mi = 0; mi < 4; ++mi)
        a[mi] = *(const half8_t*)(As + (wr * 64 + mi * 16 + (lane & 15)) * 64 +
                                  kk * 32 + (lane >> 4) * 8);
#pragma unroll
      for (int ni = 0; ni < 4; ++ni)
        b[ni] = *(const half8_t*)(Bs + (wc * 64 + ni * 16 + (lane & 15)) * 64 +
                                  kk * 32 + (lane >> 4) * 8);
#pragma unroll
      for (int mi = 0; mi < 4; ++mi)
#pragma unroll
        for (int ni = 0; ni < 4; ++ni)
          acc[mi][ni] = __builtin_amdgcn_mfma_f32_16x16x32_f16(
              a[mi], b[ni], acc[mi][ni], 0, 0, 0);
    }
    __syncthreads();
  }

  const float scale = 0x1p-20f;
  int rbase = bm * 128 + wr * 64 + (lane >> 4) * 4;
  int cbase = bn * 128 + wc * 64 + (lane & 15);
#pragma unroll
  for (int mi = 0; mi < 4; ++mi)
#pragma unroll
    for (int ni = 0; ni < 4; ++ni) {
      int col = cbase + ni * 16;
      float be = b_enc[col];
#pragma unroll
      for (int r = 0; r < 4; ++r) {
        int row = rbase + mi * 16 + r;
        h[(size_t)row * NLAT + col] = (half_t)(acc[mi][ni][r] * scale + be);
      }
    }
}

// ---------------- kernel 3: candidate collection (13-bit fp16-key histogram) ----------------
__global__ __launch_bounds__(256) void cand_kernel(
    const half_t* __restrict__ h, int* __restrict__ candIdx,
    int* __restrict__ candCnt, int r0) {
  int rl = blockIdx.x, tid = threadIdx.x;
  int rg = r0 + rl;
  const ushort8_t* ph8 = (const ushort8_t*)(h + (size_t)rl * NLAT);
  __shared__ uint32_t hist[8192];   // 32KB, bucket = 8 fp16-ulp
  __shared__ int chunkSum[256];
  __shared__ float sThresh;
  __shared__ int cCount;

  for (int i = tid; i < 8192; i += 256) hist[i] = 0;
  if (tid == 0) cCount = 0;
  __syncthreads();

  for (int i = 0; i < 8; ++i) {
    ushort8_t v = ph8[tid + i * 256];
#pragma unroll
    for (int e = 0; e < 8; ++e)
      atomicAdd(&hist[okey16((uint32_t)v[e]) >> 3], 1u);
  }
  __syncthreads();
  {
    int s = 0;
    for (int b = 0; b < 32; ++b) s += (int)hist[tid * 32 + b];
    chunkSum[tid] = s;
  }
  __syncthreads();
  if (tid == 0) {
    int cum = 0, cchunk = 255;
    for (; cchunk > 0; --cchunk) {
      if (cum + chunkSum[cchunk] >= 32) break;
      cum += chunkSum[cchunk];
    }
    int b = cchunk * 32 + 31;
    for (; b > 0; --b) {
      if (cum + (int)hist[b] >= 32) break;
      cum += (int)hist[b];
    }
    // bucket lower edge minus margin; margin 0.02 >= 2*(fp16 GEMM noise
    // ~5e-3 + fp16 storage rounding ~1e-3) at far tail
    sThresh = inv_okey16((uint32_t)b << 3) - 0.02f;
  }
  __syncthreads();
  float thresh = sThresh;

  for (int i = 0; i < 8; ++i) {
    ushort8_t v = ph8[tid + i * 256];
#pragma unroll
    for (int e = 0; e < 8; ++e) {
      float f = (float)__builtin_bit_cast(_Float16, (unsigned short)v[e]);
      if (f >= thresh) {
        int j = (tid + i * 256) * 8 + e;
        int slot = atomicAdd(&cCount, 1);
        if (slot < CAND_MAX) candIdx[(size_t)rg * CAND_MAX + slot] = j;
      }
    }
  }
  __syncthreads();
  if (tid == 0) candCnt[rg] = (cCount < CAND_MAX) ? cCount : CAND_MAX;
}

// ---------------- kernel 4: fp64 candidate dots, 4-way ILP, x-row in registers ----------------
__global__ __launch_bounds__(256) void refine_dot(
    const float* __restrict__ x, const float* __restrict__ b_pre,
    const float* __restrict__ W_enc, const float* __restrict__ b_enc,
    const double* __restrict__ meanD, const double* __restrict__ normD,
    const int* __restrict__ candIdx, const int* __restrict__ candCnt,
    double* __restrict__ candV, int r0) {
  int rg = r0 + blockIdx.x;
  int tid = threadIdx.x;
  int wv = tid >> 6, ln = tid & 63;
  double mean = meanD[rg], nrm = normD[rg];
  const float* px = x + (size_t)rg * DMODEL;
  double xr[16];
#pragma unroll
  for (int u = 0; u < 16; ++u)
    xr[u] = ((double)px[ln + u * 64] - mean) / nrm - (double)b_pre[ln + u * 64];
  int nc = candCnt[rg];
  const int* ci = candIdx + (size_t)rg * CAND_MAX;

  for (int c0 = wv * 4; c0 < nc; c0 += 16) {
    const float* wp[4];
#pragma unroll
    for (int q = 0; q < 4; ++q) {
      int c = c0 + q;
      int j = ci[c < nc ? c : (nc - 1)];
      wp[q] = W_enc + (size_t)j * DMODEL + ln;
    }
    double a0 = 0.0, a1 = 0.0, a2 = 0.0, a3 = 0.0;
#pragma unroll
    for (int u = 0; u < 16; ++u) {
      float w0 = wp[0][u * 64];
      float w1 = wp[1][u * 64];
      float w2 = wp[2][u * 64];
      float w3 = wp[3][u * 64];
      a0 += xr[u] * (double)w0;
      a1 += xr[u] * (double)w1;
      a2 += xr[u] * (double)w2;
      a3 += xr[u] * (double)w3;
    }
    double accq[4] = {a0, a1, a2, a3};
#pragma unroll
    for (int q = 0; q < 4; ++q) {
      double s = accq[q];
      for (int off = 32; off; off >>= 1) s += __shfl_down(s, off);
      int c = c0 + q;
      if (ln == 0 && c < nc) {
        int j = ci[c];
        candV[(size_t)rg * CAND_MAX + c] = s + (double)b_enc[j];
      }
    }
  }
}

// ---------------- kernel 5: rank-count top-32 select + sparse decode (fp16 WdT) ----------------
__global__ __launch_bounds__(256) void sel_decode(
    const double* __restrict__ candV, const int* __restrict__ candIdx,
    const int* __restrict__ candCnt,
    const half_t* __restrict__ WdT, const float* __restrict__ b_pre,
    const float* __restrict__ meanF, const float* __restrict__ normF,
    float* __restrict__ out, int r0) {
  int rg = r0 + blockIdx.x, tid = threadIdx.x;
  __shared__ double cV[CAND_MAX];
  __shared__ int cI[CAND_MAX];
  __shared__ float sVal[32];
  __shared__ int sIdx[32];
  int nc = candCnt[rg];
  for (int c = tid; c < nc; c += 256) {
    cV[c] = candV[(size_t)rg * CAND_MAX + c];
    cI[c] = candIdx[(size_t)rg * CAND_MAX + c];
  }
  if (tid < 32) { sVal[tid] = 0.0f; sIdx[tid] = 0; }
  __syncthreads();
  // rank-count selection: (value desc, index asc) total order; top-32 have rank<32
  for (int c = tid; c < nc; c += 256) {
    double v = cV[c];
    int ix = cI[c];
    int rank = 0;
    for (int o = 0; o < nc; ++o) {
      double vo = cV[o];
      int io = cI[o];
      rank += (vo > v || (vo == v && io < ix)) ? 1 : 0;
    }
    if (rank < 32) {
      sIdx[rank] = ix;
      sVal[rank] = (float)(v > 0.0 ? v : 0.0);  // relu
    }
  }
  __syncthreads();
  // sparse decode
  int d0 = tid * 4;
  float4 accv = {0.f, 0.f, 0.f, 0.f};
#pragma unroll 8
  for (int k = 0; k < 32; ++k) {
    float vk = sVal[k];
    const half4_t wv = *(const half4_t*)(WdT + (size_t)sIdx[k] * DMODEL + d0);
    accv.x += vk * (float)wv[0]; accv.y += vk * (float)wv[1];
    accv.z += vk * (float)wv[2]; accv.w += vk * (float)wv[3];
  }
  float4 bp = ((const float4*)b_pre)[tid];
  float nrm = normF[rg], mn = meanF[rg];
  float4 o;
  o.x = (accv.x + bp.x) * nrm + mn;
  o.y = (accv.y + bp.y) * nrm + mn;
  o.z = (accv.z + bp.z) * nrm + mn;
  o.w = (accv.w + bp.w) * nrm + mn;
  ((float4*)(out + (size_t)rg * DMODEL))[tid] = o;
}

// ---------------- launcher ----------------
extern "C" void kernel_launch(void* const* d_in, const int* in_sizes, int n_in,
                              void* d_out, int out_size, void* d_ws, size_t ws_size,
                              hipStream_t stream) {
  const float* x     = (const float*)d_in[0];
  const float* b_pre = (const float*)d_in[1];
  const float* W_enc = (const float*)d_in[2];
  const float* b_enc = (const float*)d_in[3];
  const float* W_dec = (const float*)d_in[4];
  float* out = (float*)d_out;
  char* ws = (char*)d_ws;

  // pick largest row-batch that fits ws_size
  int rowsB = NROWS;
  while (rowsB > 128) {
    size_t need = oBatch + (size_t)rowsB * BATCH_ROW_BYTES;
    if (need <= ws_size) break;
    rowsB >>= 1;
  }
  if (oBatch + (size_t)rowsB * BATCH_ROW_BYTES > ws_size) return;  // fail soft

  half_t* W0 = (half_t*)(ws + oW0);
  half_t* WdT = (half_t*)(ws + oWdT);
  float* meanF = (float*)(ws + oMeanF);
  float* normF = (float*)(ws + oNormF);
  double* meanD = (double*)(ws + oMeanD);
  double* normD = (double*)(ws + oNormD);
  int*   candCnt = (int*)(ws + oCandC);
  int*   candIdx = (int*)(ws + oCandI);
  double* candV  = (double*)(ws + oCandV);
  half_t* X0b  = (half_t*)(ws + oBatch);
  half_t* hb   = X0b + (size_t)rowsB * DMODEL;

  for (int r0 = 0; r0 < NROWS; r0 += rowsB) {
    // fused: W_enc split (only useful data for this batch's GEMM) + W_dec
    // transpose + per-row normalize. Weight parts are re-done per batch only
    // if multiple batches (rowsB<4096); with full batch it's one dispatch.
    hipLaunchKernelGGL(prepro_kernel,
                       dim3(WSPLIT_B + TRANS_B + rowsB), dim3(256), 0, stream,
                       x, b_pre, W_enc, W_dec, W0, WdT, X0b,
                       meanF, normF, meanD, normD, r0);
    hipLaunchKernelGGL(gemm_enc, dim3(NLAT / 128, rowsB / 128), dim3(256), 0, stream,
                       X0b, W0, b_enc, hb);
    hipLaunchKernelGGL(cand_kernel, dim3(rowsB), dim3(256), 0, stream,
                       hb, candIdx, candCnt, r0);
    hipLaunchKernelGGL(refine_dot, dim3(rowsB), dim3(256), 0, stream,
                       x, b_pre, W_enc, b_enc, meanD, normD, candIdx, candCnt,
                       candV, r0);
    hipLaunchKernelGGL(sel_decode, dim3(rowsB), dim3(256), 0, stream,
                       candV, candIdx, candCnt, WdT, b_pre, meanF, normF, out, r0);
  }
}

// Round 10
// 378.158 us; speedup vs baseline: 2.0843x; 1.0136x over previous
//
#include <hip/hip_runtime.h>
#include <cstdint>
#include <cstddef>

typedef _Float16 half_t;
typedef _Float16 half4_t __attribute__((ext_vector_type(4)));
typedef _Float16 half8_t __attribute__((ext_vector_type(8)));
typedef unsigned short ushort8_t __attribute__((ext_vector_type(8)));
typedef float floatx4 __attribute__((ext_vector_type(4)));

#define NROWS 4096
#define DMODEL 1024
#define NLAT 16384
#define CAND_MAX 256

// ---------------- ws layout (bytes) ----------------
#define MBYTE (1ull << 20)
static const size_t oW0    = 0;                           // 32MB fp16 W_enc*1024
static const size_t oWdT   = 32 * MBYTE;                  // 32MB fp16 W_dec^T
static const size_t oMeanF = 64 * MBYTE;                  // 16KB
static const size_t oNormF = 64 * MBYTE + (64ull << 10);
static const size_t oMeanD = 64 * MBYTE + (128ull << 10); // 32KB
static const size_t oNormD = 64 * MBYTE + (192ull << 10); // 32KB
static const size_t oCandC = 64 * MBYTE + (256ull << 10); // 16KB
static const size_t oCandI = 65 * MBYTE;                  // 4096*256*4 = 4MB
static const size_t oCandV = 69 * MBYTE;                  // 4096*256*8 = 8MB
static const size_t oBatch = 77 * MBYTE;

// per-row batch bytes: X0 fp16 (2048) + hb fp16 (32768)
#define BATCH_ROW_BYTES 34816ull

// ---------------- helpers ----------------
__device__ __forceinline__ void gload16(const void* g, void* l) {
  __builtin_amdgcn_global_load_lds(
      (const __attribute__((address_space(1))) void*)g,
      (__attribute__((address_space(3))) void*)l, 16, 0, 0);
}

// order-preserving key on fp16 bit patterns (13-bit bucket = 8 ulp wide)
__device__ __forceinline__ uint32_t okey16(uint32_t u) {
  return (u & 0x8000u) ? ((~u) & 0xFFFFu) : (u | 0x8000u);
}
__device__ __forceinline__ float inv_okey16(uint32_t k) {
  unsigned short u = (k & 0x8000u) ? (unsigned short)(k & 0x7FFFu)
                                   : (unsigned short)(~k);
  return (float)__builtin_bit_cast(_Float16, u);
}

// ---------------- kernel 1: fused preprocessing ----------------
#define WSPLIT_B 2048
#define TRANS_B  4096   // (NLAT/64) * (DMODEL/64)
__global__ __launch_bounds__(256) void prepro_kernel(
    const float* __restrict__ x, const float* __restrict__ b_pre,
    const float* __restrict__ W_enc, const float* __restrict__ Wd,
    half_t* __restrict__ W0h, half_t* __restrict__ WdT,
    half_t* __restrict__ X0,
    float* __restrict__ meanF, float* __restrict__ normF,
    double* __restrict__ meanD, double* __restrict__ normD, int r0) {
  int bid = blockIdx.x, tid = threadIdx.x;
  if (bid < WSPLIT_B) {
    size_t base = (size_t)bid * 2048 + tid;
    for (int it = 0; it < 8; ++it) {
      size_t i = base + (size_t)it * 256;
      float4 v = ((const float4*)W_enc)[i];
      half4_t h0;
      h0[0] = (half_t)(v.x * 1024.0f);
      h0[1] = (half_t)(v.y * 1024.0f);
      h0[2] = (half_t)(v.z * 1024.0f);
      h0[3] = (half_t)(v.w * 1024.0f);
      ((half4_t*)W0h)[i] = h0;
    }
    return;
  }
  if (bid < WSPLIT_B + TRANS_B) {
    __shared__ float tile[64][65];
    int t = bid - WSPLIT_B;
    int c0 = (t & 255) * 64;   // over NLAT
    int r0t = (t >> 8) * 64;   // over DMODEL
    int tc = tid & 63, tg = tid >> 6;
    for (int i = 0; i < 16; ++i) {
      int rr = i * 4 + tg;
      tile[rr][tc] = Wd[(size_t)(r0t + rr) * NLAT + c0 + tc];
    }
    __syncthreads();
    for (int i = 0; i < 16; ++i) {
      int cc = i * 4 + tg;
      WdT[(size_t)(c0 + cc) * DMODEL + r0t + tc] = (half_t)tile[tc][cc];
    }
    return;
  }
  int rl = bid - WSPLIT_B - TRANS_B;
  int rg = r0 + rl;
  const float4* px = (const float4*)(x + (size_t)rg * DMODEL);
  float4 v = px[tid];
  double s  = (double)v.x + (double)v.y + (double)v.z + (double)v.w;
  double sq = (double)v.x * v.x + (double)v.y * v.y +
              (double)v.z * v.z + (double)v.w * v.w;
  for (int off = 32; off; off >>= 1) {
    s += __shfl_down(s, off);
    sq += __shfl_down(sq, off);
  }
  __shared__ double ss[4], ssq[4];
  __shared__ double sMean, sNorm;
  int wv = tid >> 6, ln = tid & 63;
  if (ln == 0) { ss[wv] = s; ssq[wv] = sq; }
  __syncthreads();
  if (tid == 0) {
    double S = ss[0] + ss[1] + ss[2] + ss[3];
    double Q = ssq[0] + ssq[1] + ssq[2] + ssq[3];
    double mean = S / (double)DMODEL;
    double var = (Q - (double)DMODEL * mean * mean) / (double)(DMODEL - 1);
    double nrm = sqrt(var) + 1e-6;
    sMean = mean; sNorm = nrm;
    meanF[rg] = (float)mean; normF[rg] = (float)nrm;
    meanD[rg] = mean;        normD[rg] = nrm;
  }
  __syncthreads();
  float mean = (float)sMean, nrm = (float)sNorm;
  const float4* pb = (const float4*)b_pre;
  float4 bp = pb[tid];
  float c[4];
  c[0] = ((v.x - mean) / nrm - bp.x) * 1024.0f;
  c[1] = ((v.y - mean) / nrm - bp.y) * 1024.0f;
  c[2] = ((v.z - mean) / nrm - bp.z) * 1024.0f;
  c[3] = ((v.w - mean) / nrm - bp.w) * 1024.0f;
  half4_t h0;
  for (int i = 0; i < 4; ++i) h0[i] = (half_t)c[i];
  ((half4_t*)(X0 + (size_t)rl * DMODEL))[tid] = h0;
}

// ---------------- kernel 2: encode GEMM, 256^2 tile, counted-vmcnt pipeline ----------------
// 512 threads = 8 waves (2M x 4N); per-wave output 128x64; BK=64; LDS 128KB dbuf.
// LDS XOR swizzle: linear gload_lds dest + pre-swizzled global src + swizzled reads.
__global__ __launch_bounds__(512, 2) void gemm_enc(
    const half_t* __restrict__ X0, const half_t* __restrict__ W0,
    const float* __restrict__ b_enc, half_t* __restrict__ h, int mtiles) {
  __shared__ __align__(16) half_t As[2][256 * 64];
  __shared__ __align__(16) half_t Bs[2][256 * 64];
  int tid = threadIdx.x;
  int lane = tid & 63, wave = tid >> 6;
  int wm = wave >> 2, wn = wave & 3;

  // XCD ownership: xcd owns bn chunk of 8 (8*256 cols * 1024 * 2B = 4MB W0 -> L2)
  int bid = blockIdx.x;
  int xcd = bid & 7, q = bid >> 3;
  int bn = xcd * 8 + (q & 7);
  int bm = q >> 3;
  (void)mtiles;

  const char* Ag = (const char*)(X0 + (size_t)bm * 256 * DMODEL);
  const char* Bg = (const char*)(W0 + (size_t)bn * 256 * DMODEL);

  int srcSwz = ((lane & 7) ^ (lane >> 3)) << 4;   // pre-swizzled source col-byte
  int rowBase = wave * 8 + (lane >> 3);
  int ldsWOff = wave * 1024;                      // wave-uniform LDS byte base

#define STAGE(b, kt)                                                          \
  {                                                                           \
    int colB = (kt) * 128 + srcSwz;                                           \
    _Pragma("unroll") for (int i = 0; i < 4; ++i) {                           \
      size_t go = (size_t)(i * 64 + rowBase) * 2048 + colB;                   \
      gload16(Ag + go, (char*)As[b] + i * 8192 + ldsWOff);                    \
      gload16(Bg + go, (char*)Bs[b] + i * 8192 + ldsWOff);                    \
    }                                                                         \
  }

  floatx4 acc[8][4] = {};

  STAGE(0, 0);
  STAGE(1, 1);
  asm volatile("s_waitcnt vmcnt(8)" ::: "memory");
  __builtin_amdgcn_sched_barrier(0);
  __builtin_amdgcn_s_barrier();
  __builtin_amdgcn_sched_barrier(0);

  int laneQ = (lane & 15) * 128 + (lane >> 4) * 16;
  int sxor = (lane & 7) << 4;                     // read-side swizzle
  int aRow = wm * 128 * 128;                      // byte offset of wave's A rows
  int bRow = wn * 64 * 128;

  for (int kt = 0; kt < 16; ++kt) {
    int cur = kt & 1;
    const char* Ab = (const char*)As[cur];
    const char* Bb = (const char*)Bs[cur];
    for (int kk = 0; kk < 2; ++kk) {
      int kOff = kk * 64 + laneQ;
      half8_t a[8], b[4];
#pragma unroll
      for (int mi = 0; mi < 8; ++mi)
        a[mi] = *(const half8_t*)(Ab + ((aRow + mi * 2048 + kOff) ^ sxor));
#pragma unroll
      for (int ni = 0; ni < 4; ++ni)
        b[ni] = *(const half8_t*)(Bb + ((bRow + ni * 2048 + kOff) ^ sxor));
      __builtin_amdgcn_s_setprio(1);
#pragma unroll
      for (int mi = 0; mi < 8; ++mi)
#pragma unroll
        for (int ni = 0; ni < 4; ++ni)
          acc[mi][ni] = __builtin_amdgcn_mfma_f32_16x16x32_f16(
              a[mi], b[ni], acc[mi][ni], 0, 0, 0);
      __builtin_amdgcn_s_setprio(0);
    }
    if (kt == 15) break;
    __builtin_amdgcn_s_barrier();        // all waves done reading buf[cur]
    if (kt + 2 < 16) {
      STAGE(cur, kt + 2);                // refill freed buffer (8 loads in flight)
      asm volatile("s_waitcnt vmcnt(8)" ::: "memory");  // kt+1's loads landed
    } else {
      asm volatile("s_waitcnt vmcnt(0)" ::: "memory");
    }
    __builtin_amdgcn_sched_barrier(0);
    __builtin_amdgcn_s_barrier();        // buf[kt+1] ready for all waves
    __builtin_amdgcn_sched_barrier(0);
  }
#undef STAGE

  const float scale = 0x1p-20f;
  int rowb = bm * 256 + wm * 128 + ((lane >> 4) * 4);
  int colb = bn * 256 + wn * 64 + (lane & 15);
  float be[4];
#pragma unroll
  for (int ni = 0; ni < 4; ++ni) be[ni] = b_enc[colb + ni * 16];
#pragma unroll
  for (int mi = 0; mi < 8; ++mi)
#pragma unroll
    for (int ni = 0; ni < 4; ++ni)
#pragma unroll
      for (int r = 0; r < 4; ++r)
        h[(size_t)(rowb + mi * 16 + r) * NLAT + colb + ni * 16] =
            (half_t)(acc[mi][ni][r] * scale + be[ni]);
}

// ---------------- kernel 3: candidate collection (13-bit fp16-key histogram) ----------------
__global__ __launch_bounds__(256) void cand_kernel(
    const half_t* __restrict__ h, int* __restrict__ candIdx,
    int* __restrict__ candCnt, int r0) {
  int rl = blockIdx.x, tid = threadIdx.x;
  int rg = r0 + rl;
  const ushort8_t* ph8 = (const ushort8_t*)(h + (size_t)rl * NLAT);
  __shared__ uint32_t hist[8192];   // 32KB, bucket = 8 fp16-ulp
  __shared__ int chunkSum[256];
  __shared__ float sThresh;
  __shared__ int cCount;

  for (int i = tid; i < 8192; i += 256) hist[i] = 0;
  if (tid == 0) cCount = 0;
  __syncthreads();

  for (int i = 0; i < 8; ++i) {
    ushort8_t v = ph8[tid + i * 256];
#pragma unroll
    for (int e = 0; e < 8; ++e)
      atomicAdd(&hist[okey16((uint32_t)v[e]) >> 3], 1u);
  }
  __syncthreads();
  {
    int s = 0;
    for (int b = 0; b < 32; ++b) s += (int)hist[tid * 32 + b];
    chunkSum[tid] = s;
  }
  __syncthreads();
  if (tid == 0) {
    int cum = 0, cchunk = 255;
    for (; cchunk > 0; --cchunk) {
      if (cum + chunkSum[cchunk] >= 32) break;
      cum += chunkSum[cchunk];
    }
    int b = cchunk * 32 + 31;
    for (; b > 0; --b) {
      if (cum + (int)hist[b] >= 32) break;
      cum += (int)hist[b];
    }
    sThresh = inv_okey16((uint32_t)b << 3) - 0.02f;
  }
  __syncthreads();
  float thresh = sThresh;

  for (int i = 0; i < 8; ++i) {
    ushort8_t v = ph8[tid + i * 256];
#pragma unroll
    for (int e = 0; e < 8; ++e) {
      float f = (float)__builtin_bit_cast(_Float16, (unsigned short)v[e]);
      if (f >= thresh) {
        int j = (tid + i * 256) * 8 + e;
        int slot = atomicAdd(&cCount, 1);
        if (slot < CAND_MAX) candIdx[(size_t)rg * CAND_MAX + slot] = j;
      }
    }
  }
  __syncthreads();
  if (tid == 0) candCnt[rg] = (cCount < CAND_MAX) ? cCount : CAND_MAX;
}

// ---------------- kernel 4: fp64 candidate dots, 4-way ILP, x-row in registers ----------------
__global__ __launch_bounds__(256) void refine_dot(
    const float* __restrict__ x, const float* __restrict__ b_pre,
    const float* __restrict__ W_enc, const float* __restrict__ b_enc,
    const double* __restrict__ meanD, const double* __restrict__ normD,
    const int* __restrict__ candIdx, const int* __restrict__ candCnt,
    double* __restrict__ candV, int r0) {
  int rg = r0 + blockIdx.x;
  int tid = threadIdx.x;
  int wv = tid >> 6, ln = tid & 63;
  double mean = meanD[rg], nrm = normD[rg];
  const float* px = x + (size_t)rg * DMODEL;
  double xr[16];
#pragma unroll
  for (int u = 0; u < 16; ++u)
    xr[u] = ((double)px[ln + u * 64] - mean) / nrm - (double)b_pre[ln + u * 64];
  int nc = candCnt[rg];
  const int* ci = candIdx + (size_t)rg * CAND_MAX;

  for (int c0 = wv * 4; c0 < nc; c0 += 16) {
    const float* wp[4];
#pragma unroll
    for (int q = 0; q < 4; ++q) {
      int c = c0 + q;
      int j = ci[c < nc ? c : (nc - 1)];
      wp[q] = W_enc + (size_t)j * DMODEL + ln;
    }
    double a0 = 0.0, a1 = 0.0, a2 = 0.0, a3 = 0.0;
#pragma unroll
    for (int u = 0; u < 16; ++u) {
      float w0 = wp[0][u * 64];
      float w1 = wp[1][u * 64];
      float w2 = wp[2][u * 64];
      float w3 = wp[3][u * 64];
      a0 += xr[u] * (double)w0;
      a1 += xr[u] * (double)w1;
      a2 += xr[u] * (double)w2;
      a3 += xr[u] * (double)w3;
    }
    double accq[4] = {a0, a1, a2, a3};
#pragma unroll
    for (int q = 0; q < 4; ++q) {
      double s = accq[q];
      for (int off = 32; off; off >>= 1) s += __shfl_down(s, off);
      int c = c0 + q;
      if (ln == 0 && c < nc) {
        int j = ci[c];
        candV[(size_t)rg * CAND_MAX + c] = s + (double)b_enc[j];
      }
    }
  }
}

// ---------------- kernel 5: rank-count top-32 select + sparse decode (fp16 WdT) ----------------
__global__ __launch_bounds__(256) void sel_decode(
    const double* __restrict__ candV, const int* __restrict__ candIdx,
    const int* __restrict__ candCnt,
    const half_t* __restrict__ WdT, const float* __restrict__ b_pre,
    const float* __restrict__ meanF, const float* __restrict__ normF,
    float* __restrict__ out, int r0) {
  int rg = r0 + blockIdx.x, tid = threadIdx.x;
  __shared__ double cV[CAND_MAX];
  __shared__ int cI[CAND_MAX];
  __shared__ float sVal[32];
  __shared__ int sIdx[32];
  int nc = candCnt[rg];
  for (int c = tid; c < nc; c += 256) {
    cV[c] = candV[(size_t)rg * CAND_MAX + c];
    cI[c] = candIdx[(size_t)rg * CAND_MAX + c];
  }
  if (tid < 32) { sVal[tid] = 0.0f; sIdx[tid] = 0; }
  __syncthreads();
  for (int c = tid; c < nc; c += 256) {
    double v = cV[c];
    int ix = cI[c];
    int rank = 0;
    for (int o = 0; o < nc; ++o) {
      double vo = cV[o];
      int io = cI[o];
      rank += (vo > v || (vo == v && io < ix)) ? 1 : 0;
    }
    if (rank < 32) {
      sIdx[rank] = ix;
      sVal[rank] = (float)(v > 0.0 ? v : 0.0);  // relu
    }
  }
  __syncthreads();
  int d0 = tid * 4;
  float4 accv = {0.f, 0.f, 0.f, 0.f};
#pragma unroll 8
  for (int k = 0; k < 32; ++k) {
    float vk = sVal[k];
    const half4_t wv = *(const half4_t*)(WdT + (size_t)sIdx[k] * DMODEL + d0);
    accv.x += vk * (float)wv[0]; accv.y += vk * (float)wv[1];
    accv.z += vk * (float)wv[2]; accv.w += vk * (float)wv[3];
  }
  float4 bp = ((const float4*)b_pre)[tid];
  float nrm = normF[rg], mn = meanF[rg];
  float4 o;
  o.x = (accv.x + bp.x) * nrm + mn;
  o.y = (accv.y + bp.y) * nrm + mn;
  o.z = (accv.z + bp.z) * nrm + mn;
  o.w = (accv.w + bp.w) * nrm + mn;
  ((float4*)(out + (size_t)rg * DMODEL))[tid] = o;
}

// ---------------- launcher ----------------
extern "C" void kernel_launch(void* const* d_in, const int* in_sizes, int n_in,
                              void* d_out, int out_size, void* d_ws, size_t ws_size,
                              hipStream_t stream) {
  const float* x     = (const float*)d_in[0];
  const float* b_pre = (const float*)d_in[1];
  const float* W_enc = (const float*)d_in[2];
  const float* b_enc = (const float*)d_in[3];
  const float* W_dec = (const float*)d_in[4];
  float* out = (float*)d_out;
  char* ws = (char*)d_ws;

  // pick largest row-batch that fits ws_size (min 256 for 256-row GEMM tiles)
  int rowsB = NROWS;
  while (rowsB > 256) {
    size_t need = oBatch + (size_t)rowsB * BATCH_ROW_BYTES;
    if (need <= ws_size) break;
    rowsB >>= 1;
  }
  if (oBatch + (size_t)rowsB * BATCH_ROW_BYTES > ws_size) return;  // fail soft

  half_t* W0 = (half_t*)(ws + oW0);
  half_t* WdT = (half_t*)(ws + oWdT);
  float* meanF = (float*)(ws + oMeanF);
  float* normF = (float*)(ws + oNormF);
  double* meanD = (double*)(ws + oMeanD);
  double* normD = (double*)(ws + oNormD);
  int*   candCnt = (int*)(ws + oCandC);
  int*   candIdx = (int*)(ws + oCandI);
  double* candV  = (double*)(ws + oCandV);
  half_t* X0b  = (half_t*)(ws + oBatch);
  half_t* hb   = X0b + (size_t)rowsB * DMODEL;

  for (int r0 = 0; r0 < NROWS; r0 += rowsB) {
    hipLaunchKernelGGL(prepro_kernel,
                       dim3(WSPLIT_B + TRANS_B + rowsB), dim3(256), 0, stream,
                       x, b_pre, W_enc, W_dec, W0, WdT, X0b,
                       meanF, normF, meanD, normD, r0);
    int mtiles = rowsB / 256;
    hipLaunchKernelGGL(gemm_enc, dim3(mtiles * 64), dim3(512), 0, stream,
                       X0b, W0, b_enc, hb, mtiles);
    hipLaunchKernelGGL(cand_kernel, dim3(rowsB), dim3(256), 0, stream,
                       hb, candIdx, candCnt, r0);
    hipLaunchKernelGGL(refine_dot, dim3(rowsB), dim3(256), 0, stream,
                       x, b_pre, W_enc, b_enc, meanD, normD, candIdx, candCnt,
                       candV, r0);
    hipLaunchKernelGGL(sel_decode, dim3(rowsB), dim3(256), 0, stream,
                       candV, candIdx, candCnt, WdT, b_pre, meanF, normF, out, r0);
  }
}

// Round 11
// 372.689 us; speedup vs baseline: 2.1149x; 1.0147x over previous
//
#include <hip/hip_runtime.h>
#include <cstdint>
#include <cstddef>

typedef _Float16 half_t;
typedef _Float16 half4_t __attribute__((ext_vector_type(4)));
typedef _Float16 half8_t __attribute__((ext_vector_type(8)));
typedef unsigned short ushort8_t __attribute__((ext_vector_type(8)));
typedef float floatx4 __attribute__((ext_vector_type(4)));

#define NROWS 4096
#define DMODEL 1024
#define NLAT 16384
#define CAND_MAX 256

// ---------------- ws layout (bytes) ----------------
#define MBYTE (1ull << 20)
static const size_t oW0    = 0;                           // 32MB fp16 W_enc*1024
static const size_t oWdT   = 32 * MBYTE;                  // 32MB fp16 W_dec^T
static const size_t oMeanF = 64 * MBYTE;                  // 16KB
static const size_t oNormF = 64 * MBYTE + (64ull << 10);
static const size_t oMeanD = 64 * MBYTE + (128ull << 10); // 32KB
static const size_t oNormD = 64 * MBYTE + (192ull << 10); // 32KB
static const size_t oCandC = 64 * MBYTE + (256ull << 10); // 16KB
static const size_t oCandI = 65 * MBYTE;                  // 4096*256*4 = 4MB
static const size_t oCandV = 69 * MBYTE;                  // 4096*256*8 = 8MB
static const size_t oBatch = 77 * MBYTE;

// per-row batch bytes: X0 fp16 (2048) + hb fp16 (32768)
#define BATCH_ROW_BYTES 34816ull

// ---------------- helpers ----------------
__device__ __forceinline__ void gload16(const void* g, void* l) {
  __builtin_amdgcn_global_load_lds(
      (const __attribute__((address_space(1))) void*)g,
      (__attribute__((address_space(3))) void*)l, 16, 0, 0);
}

// order-preserving key on fp16 bit patterns (13-bit bucket = 8 ulp wide)
__device__ __forceinline__ uint32_t okey16(uint32_t u) {
  return (u & 0x8000u) ? ((~u) & 0xFFFFu) : (u | 0x8000u);
}
__device__ __forceinline__ float inv_okey16(uint32_t k) {
  unsigned short u = (k & 0x8000u) ? (unsigned short)(k & 0x7FFFu)
                                   : (unsigned short)(~k);
  return (float)__builtin_bit_cast(_Float16, u);
}

// ---------------- kernel 1: fused preprocessing ----------------
#define WSPLIT_B 2048
#define TRANS_B  4096   // (NLAT/64) * (DMODEL/64)
__global__ __launch_bounds__(256) void prepro_kernel(
    const float* __restrict__ x, const float* __restrict__ b_pre,
    const float* __restrict__ W_enc, const float* __restrict__ Wd,
    half_t* __restrict__ W0h, half_t* __restrict__ WdT,
    half_t* __restrict__ X0,
    float* __restrict__ meanF, float* __restrict__ normF,
    double* __restrict__ meanD, double* __restrict__ normD, int r0) {
  int bid = blockIdx.x, tid = threadIdx.x;
  if (bid < WSPLIT_B) {
    size_t base = (size_t)bid * 2048 + tid;
    for (int it = 0; it < 8; ++it) {
      size_t i = base + (size_t)it * 256;
      float4 v = ((const float4*)W_enc)[i];
      half4_t h0;
      h0[0] = (half_t)(v.x * 1024.0f);
      h0[1] = (half_t)(v.y * 1024.0f);
      h0[2] = (half_t)(v.z * 1024.0f);
      h0[3] = (half_t)(v.w * 1024.0f);
      ((half4_t*)W0h)[i] = h0;
    }
    return;
  }
  if (bid < WSPLIT_B + TRANS_B) {
    __shared__ float tile[64][65];
    int t = bid - WSPLIT_B;
    int c0 = (t & 255) * 64;   // over NLAT
    int r0t = (t >> 8) * 64;   // over DMODEL
    int tc = tid & 63, tg = tid >> 6;
    for (int i = 0; i < 16; ++i) {
      int rr = i * 4 + tg;
      tile[rr][tc] = Wd[(size_t)(r0t + rr) * NLAT + c0 + tc];
    }
    __syncthreads();
    for (int i = 0; i < 16; ++i) {
      int cc = i * 4 + tg;
      WdT[(size_t)(c0 + cc) * DMODEL + r0t + tc] = (half_t)tile[tc][cc];
    }
    return;
  }
  int rl = bid - WSPLIT_B - TRANS_B;
  int rg = r0 + rl;
  const float4* px = (const float4*)(x + (size_t)rg * DMODEL);
  float4 v = px[tid];
  double s  = (double)v.x + (double)v.y + (double)v.z + (double)v.w;
  double sq = (double)v.x * v.x + (double)v.y * v.y +
              (double)v.z * v.z + (double)v.w * v.w;
  for (int off = 32; off; off >>= 1) {
    s += __shfl_down(s, off);
    sq += __shfl_down(sq, off);
  }
  __shared__ double ss[4], ssq[4];
  __shared__ double sMean, sNorm;
  int wv = tid >> 6, ln = tid & 63;
  if (ln == 0) { ss[wv] = s; ssq[wv] = sq; }
  __syncthreads();
  if (tid == 0) {
    double S = ss[0] + ss[1] + ss[2] + ss[3];
    double Q = ssq[0] + ssq[1] + ssq[2] + ssq[3];
    double mean = S / (double)DMODEL;
    double var = (Q - (double)DMODEL * mean * mean) / (double)(DMODEL - 1);
    double nrm = sqrt(var) + 1e-6;
    sMean = mean; sNorm = nrm;
    meanF[rg] = (float)mean; normF[rg] = (float)nrm;
    meanD[rg] = mean;        normD[rg] = nrm;
  }
  __syncthreads();
  float mean = (float)sMean, nrm = (float)sNorm;
  const float4* pb = (const float4*)b_pre;
  float4 bp = pb[tid];
  float c[4];
  c[0] = ((v.x - mean) / nrm - bp.x) * 1024.0f;
  c[1] = ((v.y - mean) / nrm - bp.y) * 1024.0f;
  c[2] = ((v.z - mean) / nrm - bp.z) * 1024.0f;
  c[3] = ((v.w - mean) / nrm - bp.w) * 1024.0f;
  half4_t h0;
  for (int i = 0; i < 4; ++i) h0[i] = (half_t)c[i];
  ((half4_t*)(X0 + (size_t)rl * DMODEL))[tid] = h0;
}

// ---------------- kernel 2: encode GEMM, 256^2, true 8-phase counted-vmcnt ----------------
// 8 waves (2M x 4N), per-wave C = 128x64. BK=64, 2 K-tiles per iteration,
// 8 phases/iter: {ds_read subtile | stage 1 half-tile | bar | lgkmcnt(0) |
// setprio MFMA x16 | bar}, vmcnt(6) at phases 4 and 8 only.
// Half-tile staging order derived from read-retirement:
//   reads per tile: ph1 B(all)+A[mh0,kk0]; ph2 A[mh1,kk0]; ph3 A[mh0,kk1]; ph4 A[mh1,kk1]
//   B halves retire after ph1; A groups {0,2} after ph3; {1,3} after ph4.
__global__ __launch_bounds__(512, 2) void gemm_enc(
    const half_t* __restrict__ X0, const half_t* __restrict__ W0,
    const float* __restrict__ b_enc, half_t* __restrict__ h, int mtiles) {
  __shared__ __align__(16) half_t As[2][256 * 64];
  __shared__ __align__(16) half_t Bs[2][256 * 64];
  int tid = threadIdx.x;
  int lane = tid & 63, wave = tid >> 6;
  int wm = wave >> 2, wn = wave & 3;

  int bid = blockIdx.x;
  int xcd = bid & 7, q = bid >> 3;
  int bn = xcd * 8 + (q & 7);
  int bm = q >> 3;
  (void)mtiles;

  const char* Ag = (const char*)(X0 + (size_t)bm * 256 * DMODEL);
  const char* Bg = (const char*)(W0 + (size_t)bn * 256 * DMODEL);

  int srcSwz = ((lane & 7) ^ (lane >> 3)) << 4;   // pre-swizzled source col-byte
  int rowBase = wave * 8 + (lane >> 3);
  int ldsWOff = wave * 1024;                      // wave-uniform LDS byte base

  // stage one A/B "pair-half" (row groups pr, pr+2) of K-tile kt: 2 gload16
#define STG_A(b, kt, pr) { int colB = ((kt) & 15) * 128 + srcSwz;             \
    gload16(Ag + (size_t)((pr) * 64 + rowBase) * 2048 + colB,                 \
            (char*)As[b] + (pr) * 8192 + ldsWOff);                            \
    gload16(Ag + (size_t)(((pr) + 2) * 64 + rowBase) * 2048 + colB,           \
            (char*)As[b] + ((pr) + 2) * 8192 + ldsWOff); }
#define STG_B(b, kt, pr) { int colB = ((kt) & 15) * 128 + srcSwz;             \
    gload16(Bg + (size_t)((pr) * 64 + rowBase) * 2048 + colB,                 \
            (char*)Bs[b] + (pr) * 8192 + ldsWOff);                            \
    gload16(Bg + (size_t)(((pr) + 2) * 64 + rowBase) * 2048 + colB,           \
            (char*)Bs[b] + ((pr) + 2) * 8192 + ldsWOff); }

  floatx4 acc[8][4] = {};

  // prologue: tile0 complete (Bh0,Bh1,Ap0,Ap1) + tile1 (Bh0,Bh1,Ap0) = 14 loads
  STG_B(0, 0, 0); STG_B(0, 0, 1); STG_A(0, 0, 0); STG_A(0, 0, 1);
  STG_B(1, 1, 0); STG_B(1, 1, 1); STG_A(1, 1, 0);
  asm volatile("s_waitcnt vmcnt(6)" ::: "memory");  // tile0 landed
  __builtin_amdgcn_sched_barrier(0);
  __builtin_amdgcn_s_barrier();

  int laneQ = (lane & 15) * 128 + (lane >> 4) * 16;
  int sxor = (lane & 7) << 4;                     // read-side swizzle
  int aRow = wm * 128 * 128;                      // wave's A rows byte base
  int bRow = wn * 64 * 128;

  half8_t bfr[2][4], afr[4];
  const char *Ab, *Bb;

#define LD_A(mh, kk) _Pragma("unroll") for (int t = 0; t < 4; ++t)            \
    afr[t] = *(const half8_t*)(Ab + ((aRow + ((mh) * 4 + t) * 2048 +          \
                                      (kk) * 64 + laneQ) ^ sxor));
#define LD_B(kk) _Pragma("unroll") for (int t = 0; t < 4; ++t)                \
    bfr[kk][t] = *(const half8_t*)(Bb + ((bRow + t * 2048 +                   \
                                          (kk) * 64 + laneQ) ^ sxor));
#define MM(mb, kk) __builtin_amdgcn_s_setprio(1);                             \
    _Pragma("unroll") for (int mi = 0; mi < 4; ++mi)                          \
    _Pragma("unroll") for (int ni = 0; ni < 4; ++ni)                          \
      acc[(mb) + mi][ni] = __builtin_amdgcn_mfma_f32_16x16x32_f16(            \
          afr[mi], bfr[kk][ni], acc[(mb) + mi][ni], 0, 0, 0);                 \
    __builtin_amdgcn_s_setprio(0);
#define BAR() __builtin_amdgcn_s_barrier()
#define LGKM0() { asm volatile("s_waitcnt lgkmcnt(0)" ::: "memory");          \
    __builtin_amdgcn_sched_barrier(0); }
#define VM6() { asm volatile("s_waitcnt vmcnt(6)" ::: "memory");              \
    __builtin_amdgcn_sched_barrier(0); }

#pragma unroll 1
  for (int i = 0; i < 8; ++i) {
    int t0 = 2 * i;
    // ----- phases 1-4: compute tile t0 from buf0 -----
    Ab = (const char*)As[0]; Bb = (const char*)Bs[0];
    // ph1
    LD_B(0); LD_B(1); LD_A(0, 0);
    STG_A(1, t0 + 1, 1);                 // Ap1(t0+1); old Ap1(t0-1) retired
    BAR(); LGKM0(); MM(0, 0); BAR();
    // ph2
    LD_A(1, 0);
    STG_B(0, t0 + 2, 0);                 // Bh0(t0+2); Bh0(t0) retired at ph1
    BAR(); LGKM0(); MM(4, 0); BAR();
    // ph3
    LD_A(0, 1);
    STG_B(0, t0 + 2, 1);
    BAR(); LGKM0(); MM(0, 1); BAR();
    // ph4
    LD_A(1, 1);
    STG_A(0, t0 + 2, 0);                 // Ap0(t0+2); Ap0(t0) retired at ph3
    BAR(); LGKM0(); MM(4, 1);
    VM6();                               // tile t0+1 fully landed
    BAR();
    // ----- phases 5-8: compute tile t0+1 from buf1 -----
    Ab = (const char*)As[1]; Bb = (const char*)Bs[1];
    // ph5
    LD_B(0); LD_B(1); LD_A(0, 0);
    STG_A(0, t0 + 2, 1);                 // Ap1(t0+2); Ap1(t0) retired at ph4
    BAR(); LGKM0(); MM(0, 0); BAR();
    // ph6
    LD_A(1, 0);
    STG_B(1, t0 + 3, 0);                 // Bh0(t0+3); Bh0(t0+1) retired at ph5
    BAR(); LGKM0(); MM(4, 0); BAR();
    // ph7
    LD_A(0, 1);
    STG_B(1, t0 + 3, 1);
    BAR(); LGKM0(); MM(0, 1); BAR();
    // ph8
    LD_A(1, 1);
    STG_A(1, t0 + 3, 0);                 // Ap0(t0+3); Ap0(t0+1) retired at ph7
    BAR(); LGKM0(); MM(4, 1);
    VM6();                               // tile t0+2 fully landed
    BAR();
  }
#undef STG_A
#undef STG_B
#undef LD_A
#undef LD_B
#undef MM
#undef BAR
#undef LGKM0
#undef VM6

  const float scale = 0x1p-20f;
  int rowb = bm * 256 + wm * 128 + ((lane >> 4) * 4);
  int colb = bn * 256 + wn * 64 + (lane & 15);
  float be[4];
#pragma unroll
  for (int ni = 0; ni < 4; ++ni) be[ni] = b_enc[colb + ni * 16];
#pragma unroll
  for (int mi = 0; mi < 8; ++mi)
#pragma unroll
    for (int ni = 0; ni < 4; ++ni)
#pragma unroll
      for (int r = 0; r < 4; ++r)
        h[(size_t)(rowb + mi * 16 + r) * NLAT + colb + ni * 16] =
            (half_t)(acc[mi][ni][r] * scale + be[ni]);
}

// ---------------- kernel 3: candidate collection (13-bit fp16-key histogram) ----------------
__global__ __launch_bounds__(256) void cand_kernel(
    const half_t* __restrict__ h, int* __restrict__ candIdx,
    int* __restrict__ candCnt, int r0) {
  int rl = blockIdx.x, tid = threadIdx.x;
  int rg = r0 + rl;
  const ushort8_t* ph8 = (const ushort8_t*)(h + (size_t)rl * NLAT);
  __shared__ uint32_t hist[8192];   // 32KB, bucket = 8 fp16-ulp
  __shared__ int chunkSum[256];
  __shared__ float sThresh;
  __shared__ int cCount;

  for (int i = tid; i < 8192; i += 256) hist[i] = 0;
  if (tid == 0) cCount = 0;
  __syncthreads();

  for (int i = 0; i < 8; ++i) {
    ushort8_t v = ph8[tid + i * 256];
#pragma unroll
    for (int e = 0; e < 8; ++e)
      atomicAdd(&hist[okey16((uint32_t)v[e]) >> 3], 1u);
  }
  __syncthreads();
  {
    int s = 0;
    for (int b = 0; b < 32; ++b) s += (int)hist[tid * 32 + b];
    chunkSum[tid] = s;
  }
  __syncthreads();
  if (tid == 0) {
    int cum = 0, cchunk = 255;
    for (; cchunk > 0; --cchunk) {
      if (cum + chunkSum[cchunk] >= 32) break;
      cum += chunkSum[cchunk];
    }
    int b = cchunk * 32 + 31;
    for (; b > 0; --b) {
      if (cum + (int)hist[b] >= 32) break;
      cum += (int)hist[b];
    }
    sThresh = inv_okey16((uint32_t)b << 3) - 0.02f;
  }
  __syncthreads();
  float thresh = sThresh;

  for (int i = 0; i < 8; ++i) {
    ushort8_t v = ph8[tid + i * 256];
#pragma unroll
    for (int e = 0; e < 8; ++e) {
      float f = (float)__builtin_bit_cast(_Float16, (unsigned short)v[e]);
      if (f >= thresh) {
        int j = (tid + i * 256) * 8 + e;
        int slot = atomicAdd(&cCount, 1);
        if (slot < CAND_MAX) candIdx[(size_t)rg * CAND_MAX + slot] = j;
      }
    }
  }
  __syncthreads();
  if (tid == 0) candCnt[rg] = (cCount < CAND_MAX) ? cCount : CAND_MAX;
}

// ---------------- kernel 4: fp64 candidate dots, 4-way ILP, x-row in registers ----------------
__global__ __launch_bounds__(256) void refine_dot(
    const float* __restrict__ x, const float* __restrict__ b_pre,
    const float* __restrict__ W_enc, const float* __restrict__ b_enc,
    const double* __restrict__ meanD, const double* __restrict__ normD,
    const int* __restrict__ candIdx, const int* __restrict__ candCnt,
    double* __restrict__ candV, int r0) {
  int rg = r0 + blockIdx.x;
  int tid = threadIdx.x;
  int wv = tid >> 6, ln = tid & 63;
  double mean = meanD[rg], nrm = normD[rg];
  const float* px = x + (size_t)rg * DMODEL;
  double xr[16];
#pragma unroll
  for (int u = 0; u < 16; ++u)
    xr[u] = ((double)px[ln + u * 64] - mean) / nrm - (double)b_pre[ln + u * 64];
  int nc = candCnt[rg];
  const int* ci = candIdx + (size_t)rg * CAND_MAX;

  for (int c0 = wv * 4; c0 < nc; c0 += 16) {
    const float* wp[4];
#pragma unroll
    for (int q = 0; q < 4; ++q) {
      int c = c0 + q;
      int j = ci[c < nc ? c : (nc - 1)];
      wp[q] = W_enc + (size_t)j * DMODEL + ln;
    }
    double a0 = 0.0, a1 = 0.0, a2 = 0.0, a3 = 0.0;
#pragma unroll
    for (int u = 0; u < 16; ++u) {
      float w0 = wp[0][u * 64];
      float w1 = wp[1][u * 64];
      float w2 = wp[2][u * 64];
      float w3 = wp[3][u * 64];
      a0 += xr[u] * (double)w0;
      a1 += xr[u] * (double)w1;
      a2 += xr[u] * (double)w2;
      a3 += xr[u] * (double)w3;
    }
    double accq[4] = {a0, a1, a2, a3};
#pragma unroll
    for (int q = 0; q < 4; ++q) {
      double s = accq[q];
      for (int off = 32; off; off >>= 1) s += __shfl_down(s, off);
      int c = c0 + q;
      if (ln == 0 && c < nc) {
        int j = ci[c];
        candV[(size_t)rg * CAND_MAX + c] = s + (double)b_enc[j];
      }
    }
  }
}

// ---------------- kernel 5: rank-count top-32 select + sparse decode (fp16 WdT) ----------------
__global__ __launch_bounds__(256) void sel_decode(
    const double* __restrict__ candV, const int* __restrict__ candIdx,
    const int* __restrict__ candCnt,
    const half_t* __restrict__ WdT, const float* __restrict__ b_pre,
    const float* __restrict__ meanF, const float* __restrict__ normF,
    float* __restrict__ out, int r0) {
  int rg = r0 + blockIdx.x, tid = threadIdx.x;
  __shared__ double cV[CAND_MAX];
  __shared__ int cI[CAND_MAX];
  __shared__ float sVal[32];
  __shared__ int sIdx[32];
  int nc = candCnt[rg];
  for (int c = tid; c < nc; c += 256) {
    cV[c] = candV[(size_t)rg * CAND_MAX + c];
    cI[c] = candIdx[(size_t)rg * CAND_MAX + c];
  }
  if (tid < 32) { sVal[tid] = 0.0f; sIdx[tid] = 0; }
  __syncthreads();
  for (int c = tid; c < nc; c += 256) {
    double v = cV[c];
    int ix = cI[c];
    int rank = 0;
    for (int o = 0; o < nc; ++o) {
      double vo = cV[o];
      int io = cI[o];
      rank += (vo > v || (vo == v && io < ix)) ? 1 : 0;
    }
    if (rank < 32) {
      sIdx[rank] = ix;
      sVal[rank] = (float)(v > 0.0 ? v : 0.0);  // relu
    }
  }
  __syncthreads();
  int d0 = tid * 4;
  float4 accv = {0.f, 0.f, 0.f, 0.f};
#pragma unroll 8
  for (int k = 0; k < 32; ++k) {
    float vk = sVal[k];
    const half4_t wv = *(const half4_t*)(WdT + (size_t)sIdx[k] * DMODEL + d0);
    accv.x += vk * (float)wv[0]; accv.y += vk * (float)wv[1];
    accv.z += vk * (float)wv[2]; accv.w += vk * (float)wv[3];
  }
  float4 bp = ((const float4*)b_pre)[tid];
  float nrm = normF[rg], mn = meanF[rg];
  float4 o;
  o.x = (accv.x + bp.x) * nrm + mn;
  o.y = (accv.y + bp.y) * nrm + mn;
  o.z = (accv.z + bp.z) * nrm + mn;
  o.w = (accv.w + bp.w) * nrm + mn;
  ((float4*)(out + (size_t)rg * DMODEL))[tid] = o;
}

// ---------------- launcher ----------------
extern "C" void kernel_launch(void* const* d_in, const int* in_sizes, int n_in,
                              void* d_out, int out_size, void* d_ws, size_t ws_size,
                              hipStream_t stream) {
  const float* x     = (const float*)d_in[0];
  const float* b_pre = (const float*)d_in[1];
  const float* W_enc = (const float*)d_in[2];
  const float* b_enc = (const float*)d_in[3];
  const float* W_dec = (const float*)d_in[4];
  float* out = (float*)d_out;
  char* ws = (char*)d_ws;

  // pick largest row-batch that fits ws_size (min 256 for 256-row GEMM tiles)
  int rowsB = NROWS;
  while (rowsB > 256) {
    size_t need = oBatch + (size_t)rowsB * BATCH_ROW_BYTES;
    if (need <= ws_size) break;
    rowsB >>= 1;
  }
  if (oBatch + (size_t)rowsB * BATCH_ROW_BYTES > ws_size) return;  // fail soft

  half_t* W0 = (half_t*)(ws + oW0);
  half_t* WdT = (half_t*)(ws + oWdT);
  float* meanF = (float*)(ws + oMeanF);
  float* normF = (float*)(ws + oNormF);
  double* meanD = (double*)(ws + oMeanD);
  double* normD = (double*)(ws + oNormD);
  int*   candCnt = (int*)(ws + oCandC);
  int*   candIdx = (int*)(ws + oCandI);
  double* candV  = (double*)(ws + oCandV);
  half_t* X0b  = (half_t*)(ws + oBatch);
  half_t* hb   = X0b + (size_t)rowsB * DMODEL;

  for (int r0 = 0; r0 < NROWS; r0 += rowsB) {
    hipLaunchKernelGGL(prepro_kernel,
                       dim3(WSPLIT_B + TRANS_B + rowsB), dim3(256), 0, stream,
                       x, b_pre, W_enc, W_dec, W0, WdT, X0b,
                       meanF, normF, meanD, normD, r0);
    int mtiles = rowsB / 256;
    hipLaunchKernelGGL(gemm_enc, dim3(mtiles * 64), dim3(512), 0, stream,
                       X0b, W0, b_enc, hb, mtiles);
    hipLaunchKernelGGL(cand_kernel, dim3(rowsB), dim3(256), 0, stream,
                       hb, candIdx, candCnt, r0);
    hipLaunchKernelGGL(refine_dot, dim3(rowsB), dim3(256), 0, stream,
                       x, b_pre, W_enc, b_enc, meanD, normD, candIdx, candCnt,
                       candV, r0);
    hipLaunchKernelGGL(sel_decode, dim3(rowsB), dim3(256), 0, stream,
                       candV, candIdx, candCnt, WdT, b_pre, meanF, normF, out, r0);
  }
}

// Round 12
// 352.050 us; speedup vs baseline: 2.2389x; 1.0586x over previous
//
#include <hip/hip_runtime.h>
#include <cstdint>
#include <cstddef>

typedef _Float16 half_t;
typedef _Float16 half4_t __attribute__((ext_vector_type(4)));
typedef _Float16 half8_t __attribute__((ext_vector_type(8)));
typedef unsigned short ushort8_t __attribute__((ext_vector_type(8)));
typedef float floatx4 __attribute__((ext_vector_type(4)));

#define NROWS 4096
#define DMODEL 1024
#define NLAT 16384
#define CAND_MAX 256

// ---------------- ws layout (bytes) ----------------
#define MBYTE (1ull << 20)
static const size_t oW0    = 0;                           // 32MB fp16 W_enc*1024
static const size_t oWdT   = 32 * MBYTE;                  // 32MB fp16 W_dec^T
static const size_t oMeanD = 64 * MBYTE;                  // 32KB
static const size_t oNormD = 64 * MBYTE + (64ull << 10);  // 32KB
static const size_t oBatch = 65 * MBYTE;

// per-row batch bytes: X0 fp16 (2048) + hb fp16 (32768)
#define BATCH_ROW_BYTES 34816ull

// ---------------- helpers ----------------
__device__ __forceinline__ void gload16(const void* g, void* l) {
  __builtin_amdgcn_global_load_lds(
      (const __attribute__((address_space(1))) void*)g,
      (__attribute__((address_space(3))) void*)l, 16, 0, 0);
}

// order-preserving key on fp16 bit patterns (13-bit bucket = 8 ulp wide)
__device__ __forceinline__ uint32_t okey16(uint32_t u) {
  return (u & 0x8000u) ? ((~u) & 0xFFFFu) : (u | 0x8000u);
}
__device__ __forceinline__ float inv_okey16(uint32_t k) {
  unsigned short u = (k & 0x8000u) ? (unsigned short)(k & 0x7FFFu)
                                   : (unsigned short)(~k);
  return (float)__builtin_bit_cast(_Float16, u);
}

// ---------------- kernel 1: fused preprocessing ----------------
#define WSPLIT_B 2048
#define TRANS_B  4096   // (NLAT/64) * (DMODEL/64)
__global__ __launch_bounds__(256) void prepro_kernel(
    const float* __restrict__ x, const float* __restrict__ b_pre,
    const float* __restrict__ W_enc, const float* __restrict__ Wd,
    half_t* __restrict__ W0h, half_t* __restrict__ WdT,
    half_t* __restrict__ X0,
    double* __restrict__ meanD, double* __restrict__ normD, int r0) {
  int bid = blockIdx.x, tid = threadIdx.x;
  if (bid < WSPLIT_B) {
    size_t base = (size_t)bid * 2048 + tid;
    for (int it = 0; it < 8; ++it) {
      size_t i = base + (size_t)it * 256;
      float4 v = ((const float4*)W_enc)[i];
      half4_t h0;
      h0[0] = (half_t)(v.x * 1024.0f);
      h0[1] = (half_t)(v.y * 1024.0f);
      h0[2] = (half_t)(v.z * 1024.0f);
      h0[3] = (half_t)(v.w * 1024.0f);
      ((half4_t*)W0h)[i] = h0;
    }
    return;
  }
  if (bid < WSPLIT_B + TRANS_B) {
    __shared__ float tile[64][65];
    int t = bid - WSPLIT_B;
    int c0 = (t & 255) * 64;   // over NLAT
    int r0t = (t >> 8) * 64;   // over DMODEL
    int tc = tid & 63, tg = tid >> 6;
    for (int i = 0; i < 16; ++i) {
      int rr = i * 4 + tg;
      tile[rr][tc] = Wd[(size_t)(r0t + rr) * NLAT + c0 + tc];
    }
    __syncthreads();
    for (int i = 0; i < 16; ++i) {
      int cc = i * 4 + tg;
      WdT[(size_t)(c0 + cc) * DMODEL + r0t + tc] = (half_t)tile[tc][cc];
    }
    return;
  }
  int rl = bid - WSPLIT_B - TRANS_B;
  int rg = r0 + rl;
  const float4* px = (const float4*)(x + (size_t)rg * DMODEL);
  float4 v = px[tid];
  double s  = (double)v.x + (double)v.y + (double)v.z + (double)v.w;
  double sq = (double)v.x * v.x + (double)v.y * v.y +
              (double)v.z * v.z + (double)v.w * v.w;
  for (int off = 32; off; off >>= 1) {
    s += __shfl_down(s, off);
    sq += __shfl_down(sq, off);
  }
  __shared__ double ss[4], ssq[4];
  __shared__ double sMean, sNorm;
  int wv = tid >> 6, ln = tid & 63;
  if (ln == 0) { ss[wv] = s; ssq[wv] = sq; }
  __syncthreads();
  if (tid == 0) {
    double S = ss[0] + ss[1] + ss[2] + ss[3];
    double Q = ssq[0] + ssq[1] + ssq[2] + ssq[3];
    double mean = S / (double)DMODEL;
    double var = (Q - (double)DMODEL * mean * mean) / (double)(DMODEL - 1);
    double nrm = sqrt(var) + 1e-6;
    sMean = mean; sNorm = nrm;
    meanD[rg] = mean; normD[rg] = nrm;
  }
  __syncthreads();
  float mean = (float)sMean, nrm = (float)sNorm;
  const float4* pb = (const float4*)b_pre;
  float4 bp = pb[tid];
  float c[4];
  c[0] = ((v.x - mean) / nrm - bp.x) * 1024.0f;
  c[1] = ((v.y - mean) / nrm - bp.y) * 1024.0f;
  c[2] = ((v.z - mean) / nrm - bp.z) * 1024.0f;
  c[3] = ((v.w - mean) / nrm - bp.w) * 1024.0f;
  half4_t h0;
  for (int i = 0; i < 4; ++i) h0[i] = (half_t)c[i];
  ((half4_t*)(X0 + (size_t)rl * DMODEL))[tid] = h0;
}

// ---------------- kernel 2: encode GEMM, 8-phase + one-phase-ahead LDS prefetch ----------------
// 8 waves (2M x 4N), per-wave C 128x64, BK=64, 2 tiles/iter, tail-peeled.
// MFMA of phase p consumes fragments ds_read-issued in phase p-1 (lgkmcnt(4))
// so the LDS port runs concurrently with the MFMA pipe instead of serializing.
__global__ __launch_bounds__(512, 2) void gemm_enc(
    const half_t* __restrict__ X0, const half_t* __restrict__ W0,
    const float* __restrict__ b_enc, half_t* __restrict__ h, int mtiles) {
  __shared__ __align__(16) half_t As[2][256 * 64];
  __shared__ __align__(16) half_t Bs[2][256 * 64];
  int tid = threadIdx.x;
  int lane = tid & 63, wave = tid >> 6;
  int wm = wave >> 2, wn = wave & 3;

  int bid = blockIdx.x;
  int xcd = bid & 7, q = bid >> 3;
  int bn = xcd * 8 + (q & 7);
  int bm = q >> 3;
  (void)mtiles;

  const char* Ag = (const char*)(X0 + (size_t)bm * 256 * DMODEL);
  const char* Bg = (const char*)(W0 + (size_t)bn * 256 * DMODEL);

  int srcSwz = ((lane & 7) ^ (lane >> 3)) << 4;
  int rowBase = wave * 8 + (lane >> 3);
  int ldsWOff = wave * 1024;

#define STG_A(b, kt, pr) { int colB = ((kt) & 15) * 128 + srcSwz;             \
    gload16(Ag + (size_t)((pr) * 64 + rowBase) * 2048 + colB,                 \
            (char*)As[b] + (pr) * 8192 + ldsWOff);                            \
    gload16(Ag + (size_t)(((pr) + 2) * 64 + rowBase) * 2048 + colB,           \
            (char*)As[b] + ((pr) + 2) * 8192 + ldsWOff); }
#define STG_B(b, kt, pr) { int colB = ((kt) & 15) * 128 + srcSwz;             \
    gload16(Bg + (size_t)((pr) * 64 + rowBase) * 2048 + colB,                 \
            (char*)Bs[b] + (pr) * 8192 + ldsWOff);                            \
    gload16(Bg + (size_t)(((pr) + 2) * 64 + rowBase) * 2048 + colB,           \
            (char*)Bs[b] + ((pr) + 2) * 8192 + ldsWOff); }

  floatx4 acc[8][4] = {};

  // prologue: tile0 complete + tile1 minus Ap1
  STG_B(0, 0, 0); STG_B(0, 0, 1); STG_A(0, 0, 0); STG_A(0, 0, 1);
  STG_B(1, 1, 0); STG_B(1, 1, 1); STG_A(1, 1, 0);
  asm volatile("s_waitcnt vmcnt(6)" ::: "memory");
  __builtin_amdgcn_sched_barrier(0);
  __builtin_amdgcn_s_barrier();

  int laneQ = (lane & 15) * 128 + (lane >> 4) * 16;
  int sxor = (lane & 7) << 4;
  int aRow = wm * 128 * 128;
  int bRow = wn * 64 * 128;

  half8_t bfr[2][4], afA[4], afB[4];
  const char *Ab, *Bb;

#define LD_B(kk) _Pragma("unroll") for (int t = 0; t < 4; ++t)                \
    bfr[kk][t] = *(const half8_t*)(Bb + ((bRow + t * 2048 +                   \
                                          (kk) * 64 + laneQ) ^ sxor));
#define LD_AF(DST, mh, kk) _Pragma("unroll") for (int t = 0; t < 4; ++t)      \
    DST[t] = *(const half8_t*)(Ab + ((aRow + ((mh) * 4 + t) * 2048 +          \
                                      (kk) * 64 + laneQ) ^ sxor));
#define MM(mb, FR, kk) __builtin_amdgcn_s_setprio(1);                         \
    _Pragma("unroll") for (int mi = 0; mi < 4; ++mi)                          \
    _Pragma("unroll") for (int ni = 0; ni < 4; ++ni)                          \
      acc[(mb) + mi][ni] = __builtin_amdgcn_mfma_f32_16x16x32_f16(            \
          FR[mi], bfr[kk][ni], acc[(mb) + mi][ni], 0, 0, 0);                  \
    __builtin_amdgcn_s_setprio(0);
#define BAR() __builtin_amdgcn_s_barrier()
#define LGKM(n) { asm volatile("s_waitcnt lgkmcnt(" #n ")" ::: "memory");     \
    __builtin_amdgcn_sched_barrier(0); }
#define VM6() { asm volatile("s_waitcnt vmcnt(6)" ::: "memory");              \
    __builtin_amdgcn_sched_barrier(0); }
#define VM0() { asm volatile("s_waitcnt vmcnt(0)" ::: "memory");              \
    __builtin_amdgcn_sched_barrier(0); }

#pragma unroll 1
  for (int i = 0; i < 7; ++i) {
    int t0 = 2 * i;
    // ---- phases 1-4: tile t0 (buf0) ----
    Ab = (const char*)As[0]; Bb = (const char*)Bs[0];
    LD_B(0); LD_B(1); LD_AF(afA, 0, 0); LD_AF(afB, 1, 0);   // 16 reads
    STG_A(1, t0 + 1, 1);
    BAR(); LGKM(4); MM(0, afA, 0); BAR();
    LD_AF(afA, 0, 1);                                        // prefetch
    STG_B(0, t0 + 2, 0);
    BAR(); LGKM(4); MM(4, afB, 0); BAR();
    LD_AF(afB, 1, 1);                                        // prefetch
    STG_B(0, t0 + 2, 1);
    BAR(); LGKM(4); MM(0, afA, 1); BAR();
    STG_A(0, t0 + 2, 0);
    BAR(); LGKM(0); MM(4, afB, 1); VM6(); BAR();
    // ---- phases 5-8: tile t0+1 (buf1) ----
    Ab = (const char*)As[1]; Bb = (const char*)Bs[1];
    LD_B(0); LD_B(1); LD_AF(afA, 0, 0); LD_AF(afB, 1, 0);
    STG_A(0, t0 + 2, 1);
    BAR(); LGKM(4); MM(0, afA, 0); BAR();
    LD_AF(afA, 0, 1);
    STG_B(1, t0 + 3, 0);
    BAR(); LGKM(4); MM(4, afB, 0); BAR();
    LD_AF(afB, 1, 1);
    STG_B(1, t0 + 3, 1);
    BAR(); LGKM(4); MM(0, afA, 1); BAR();
    STG_A(1, t0 + 3, 0);
    BAR(); LGKM(0); MM(4, afB, 1); VM6(); BAR();
  }
  // ---- peeled i=7: tiles 14 (buf0) + 15 (buf1), no stages past 15 ----
  {
    Ab = (const char*)As[0]; Bb = (const char*)Bs[0];
    LD_B(0); LD_B(1); LD_AF(afA, 0, 0); LD_AF(afB, 1, 0);
    STG_A(1, 15, 1);                    // completes tile 15
    BAR(); LGKM(4); MM(0, afA, 0); BAR();
    LD_AF(afA, 0, 1);
    BAR(); LGKM(4); MM(4, afB, 0); BAR();
    LD_AF(afB, 1, 1);
    BAR(); LGKM(4); MM(0, afA, 1); BAR();
    BAR(); LGKM(0); MM(4, afB, 1); VM0(); BAR();
    // tile 15, no cross-wave hazards remain
    Ab = (const char*)As[1]; Bb = (const char*)Bs[1];
    LD_B(0); LD_B(1); LD_AF(afA, 0, 0); LD_AF(afB, 1, 0);
    LGKM(4); MM(0, afA, 0);
    LD_AF(afA, 0, 1);
    LGKM(4); MM(4, afB, 0);
    LD_AF(afB, 1, 1);
    LGKM(4); MM(0, afA, 1);
    LGKM(0); MM(4, afB, 1);
  }
#undef STG_A
#undef STG_B
#undef LD_B
#undef LD_AF
#undef MM
#undef BAR
#undef LGKM
#undef VM6
#undef VM0

  const float scale = 0x1p-20f;
  int rowb = bm * 256 + wm * 128 + ((lane >> 4) * 4);
  int colb = bn * 256 + wn * 64 + (lane & 15);
  float be[4];
#pragma unroll
  for (int ni = 0; ni < 4; ++ni) be[ni] = b_enc[colb + ni * 16];
#pragma unroll
  for (int mi = 0; mi < 8; ++mi)
#pragma unroll
    for (int ni = 0; ni < 4; ++ni)
#pragma unroll
      for (int r = 0; r < 4; ++r)
        h[(size_t)(rowb + mi * 16 + r) * NLAT + colb + ni * 16] =
            (half_t)(acc[mi][ni][r] * scale + be[ni]);
}

// ---------------- kernel 3: fused postprocessing (cand + fp64 refine + select + decode) ----------------
__global__ __launch_bounds__(256) void postproc(
    const half_t* __restrict__ h, const float* __restrict__ x,
    const float* __restrict__ b_pre, const float* __restrict__ W_enc,
    const float* __restrict__ b_enc,
    const double* __restrict__ meanD, const double* __restrict__ normD,
    const half_t* __restrict__ WdT, float* __restrict__ out, int r0) {
  int rl = blockIdx.x, tid = threadIdx.x;
  int rg = r0 + rl;
  int wv = tid >> 6, ln = tid & 63;
  const ushort8_t* ph8 = (const ushort8_t*)(h + (size_t)rl * NLAT);

  __shared__ uint32_t hist[8192];   // 32KB
  __shared__ int chunkSum[256];
  __shared__ float sThresh;
  __shared__ int cCount;
  __shared__ int cI[CAND_MAX];
  __shared__ double cV[CAND_MAX];
  __shared__ float sVal[32];
  __shared__ int sIdx[32];

  // fp64 normalized row fragment, register-resident (per-lane, per wave)
  double mean = meanD[rg], nrm = normD[rg];
  const float* px = x + (size_t)rg * DMODEL;
  double xr[16];
#pragma unroll
  for (int u = 0; u < 16; ++u)
    xr[u] = ((double)px[ln + u * 64] - mean) / nrm - (double)b_pre[ln + u * 64];

  // ---- phase A: 13-bit histogram over fp16 bit patterns ----
  for (int i = tid; i < 8192; i += 256) hist[i] = 0;
  if (tid == 0) cCount = 0;
  __syncthreads();
  for (int i = 0; i < 8; ++i) {
    ushort8_t v = ph8[tid + i * 256];
#pragma unroll
    for (int e = 0; e < 8; ++e)
      atomicAdd(&hist[okey16((uint32_t)v[e]) >> 3], 1u);
  }
  __syncthreads();
  {
    int s = 0;
    for (int b = 0; b < 32; ++b) s += (int)hist[tid * 32 + b];
    chunkSum[tid] = s;
  }
  __syncthreads();
  if (tid == 0) {
    int cum = 0, cchunk = 255;
    for (; cchunk > 0; --cchunk) {
      if (cum + chunkSum[cchunk] >= 32) break;
      cum += chunkSum[cchunk];
    }
    int b = cchunk * 32 + 31;
    for (; b > 0; --b) {
      if (cum + (int)hist[b] >= 32) break;
      cum += (int)hist[b];
    }
    // margin 0.02 >= 2*(fp16 GEMM noise ~5e-3 + fp16 storage rounding)
    sThresh = inv_okey16((uint32_t)b << 3) - 0.02f;
  }
  __syncthreads();
  float thresh = sThresh;

  // ---- phase B: collect candidate indices (h row is L2-hot) ----
  for (int i = 0; i < 8; ++i) {
    ushort8_t v = ph8[tid + i * 256];
#pragma unroll
    for (int e = 0; e < 8; ++e) {
      float f = (float)__builtin_bit_cast(_Float16, (unsigned short)v[e]);
      if (f >= thresh) {
        int slot = atomicAdd(&cCount, 1);
        if (slot < CAND_MAX) cI[slot] = (tid + i * 256) * 8 + e;
      }
    }
  }
  __syncthreads();
  int nc = (cCount < CAND_MAX) ? cCount : CAND_MAX;

  // ---- phase C: exact fp64 dots, 4 candidates per wave, 4-way ILP ----
  for (int c0 = wv * 4; c0 < nc; c0 += 16) {
    const float* wp[4];
#pragma unroll
    for (int qq = 0; qq < 4; ++qq) {
      int c = c0 + qq;
      int j = cI[c < nc ? c : (nc - 1)];
      wp[qq] = W_enc + (size_t)j * DMODEL + ln;
    }
    double a0 = 0.0, a1 = 0.0, a2 = 0.0, a3 = 0.0;
#pragma unroll
    for (int u = 0; u < 16; ++u) {
      float w0 = wp[0][u * 64];
      float w1 = wp[1][u * 64];
      float w2 = wp[2][u * 64];
      float w3 = wp[3][u * 64];
      a0 += xr[u] * (double)w0;
      a1 += xr[u] * (double)w1;
      a2 += xr[u] * (double)w2;
      a3 += xr[u] * (double)w3;
    }
    double accq[4] = {a0, a1, a2, a3};
#pragma unroll
    for (int qq = 0; qq < 4; ++qq) {
      double s = accq[qq];
      for (int off = 32; off; off >>= 1) s += __shfl_down(s, off);
      int c = c0 + qq;
      if (ln == 0 && c < nc) cV[c] = s + (double)b_enc[cI[c]];
    }
  }
  if (tid < 32) { sVal[tid] = 0.0f; sIdx[tid] = 0; }
  __syncthreads();

  // ---- phase D: rank-count exact top-32 (value desc, index asc) ----
  for (int c = tid; c < nc; c += 256) {
    double v = cV[c];
    int ix = cI[c];
    int rank = 0;
    for (int o = 0; o < nc; ++o) {
      double vo = cV[o];
      int io = cI[o];
      rank += (vo > v || (vo == v && io < ix)) ? 1 : 0;
    }
    if (rank < 32) {
      sIdx[rank] = ix;
      sVal[rank] = (float)(v > 0.0 ? v : 0.0);  // relu
    }
  }
  __syncthreads();

  // ---- phase E: sparse decode + denormalize ----
  int d0 = tid * 4;
  float4 accv = {0.f, 0.f, 0.f, 0.f};
#pragma unroll 8
  for (int k = 0; k < 32; ++k) {
    float vk = sVal[k];
    const half4_t wvv = *(const half4_t*)(WdT + (size_t)sIdx[k] * DMODEL + d0);
    accv.x += vk * (float)wvv[0]; accv.y += vk * (float)wvv[1];
    accv.z += vk * (float)wvv[2]; accv.w += vk * (float)wvv[3];
  }
  float4 bp = ((const float4*)b_pre)[tid];
  float nrmf = (float)nrm, mnf = (float)mean;
  float4 o;
  o.x = (accv.x + bp.x) * nrmf + mnf;
  o.y = (accv.y + bp.y) * nrmf + mnf;
  o.z = (accv.z + bp.z) * nrmf + mnf;
  o.w = (accv.w + bp.w) * nrmf + mnf;
  ((float4*)(out + (size_t)rg * DMODEL))[tid] = o;
}

// ---------------- launcher ----------------
extern "C" void kernel_launch(void* const* d_in, const int* in_sizes, int n_in,
                              void* d_out, int out_size, void* d_ws, size_t ws_size,
                              hipStream_t stream) {
  const float* x     = (const float*)d_in[0];
  const float* b_pre = (const float*)d_in[1];
  const float* W_enc = (const float*)d_in[2];
  const float* b_enc = (const float*)d_in[3];
  const float* W_dec = (const float*)d_in[4];
  float* out = (float*)d_out;
  char* ws = (char*)d_ws;

  // pick largest row-batch that fits ws_size (min 256 for 256-row GEMM tiles)
  int rowsB = NROWS;
  while (rowsB > 256) {
    size_t need = oBatch + (size_t)rowsB * BATCH_ROW_BYTES;
    if (need <= ws_size) break;
    rowsB >>= 1;
  }
  if (oBatch + (size_t)rowsB * BATCH_ROW_BYTES > ws_size) return;  // fail soft

  half_t* W0 = (half_t*)(ws + oW0);
  half_t* WdT = (half_t*)(ws + oWdT);
  double* meanD = (double*)(ws + oMeanD);
  double* normD = (double*)(ws + oNormD);
  half_t* X0b  = (half_t*)(ws + oBatch);
  half_t* hb   = X0b + (size_t)rowsB * DMODEL;

  for (int r0 = 0; r0 < NROWS; r0 += rowsB) {
    hipLaunchKernelGGL(prepro_kernel,
                       dim3(WSPLIT_B + TRANS_B + rowsB), dim3(256), 0, stream,
                       x, b_pre, W_enc, W_dec, W0, WdT, X0b, meanD, normD, r0);
    int mtiles = rowsB / 256;
    hipLaunchKernelGGL(gemm_enc, dim3(mtiles * 64), dim3(512), 0, stream,
                       X0b, W0, b_enc, hb, mtiles);
    hipLaunchKernelGGL(postproc, dim3(rowsB), dim3(256), 0, stream,
                       hb, x, b_pre, W_enc, b_enc, meanD, normD, WdT, out, r0);
  }
}

// Round 13
// 329.830 us; speedup vs baseline: 2.3897x; 1.0674x over previous
//
#include <hip/hip_runtime.h>
#include <cstdint>
#include <cstddef>

typedef _Float16 half_t;
typedef _Float16 half4_t __attribute__((ext_vector_type(4)));
typedef _Float16 half8_t __attribute__((ext_vector_type(8)));
typedef unsigned short ushort8_t __attribute__((ext_vector_type(8)));
typedef float floatx4 __attribute__((ext_vector_type(4)));

#define NROWS 4096
#define DMODEL 1024
#define NLAT 16384
#define CAND_MAX 256

// ---------------- ws layout (bytes) ----------------
#define MBYTE (1ull << 20)
static const size_t oW0    = 0;                           // 32MB fp16 W_enc*1024
static const size_t oWdT   = 32 * MBYTE;                  // 32MB fp16 W_dec^T
static const size_t oMeanD = 64 * MBYTE;                  // 32KB
static const size_t oNormD = 64 * MBYTE + (64ull << 10);  // 32KB
static const size_t oBatch = 65 * MBYTE;

// per-row batch bytes: X0 fp16 (2048) + hb fp16 (32768)
#define BATCH_ROW_BYTES 34816ull

// ---------------- helpers ----------------
__device__ __forceinline__ void gload16(const void* g, void* l) {
  __builtin_amdgcn_global_load_lds(
      (const __attribute__((address_space(1))) void*)g,
      (__attribute__((address_space(3))) void*)l, 16, 0, 0);
}

// ---------------- kernel 1: fused preprocessing ----------------
#define WSPLIT_B 2048
#define TRANS_B  4096   // (NLAT/64) * (DMODEL/64)
__global__ __launch_bounds__(256) void prepro_kernel(
    const float* __restrict__ x, const float* __restrict__ b_pre,
    const float* __restrict__ W_enc, const float* __restrict__ Wd,
    half_t* __restrict__ W0h, half_t* __restrict__ WdT,
    half_t* __restrict__ X0,
    double* __restrict__ meanD, double* __restrict__ normD, int r0) {
  int bid = blockIdx.x, tid = threadIdx.x;
  if (bid < WSPLIT_B) {
    size_t base = (size_t)bid * 2048 + tid;
    for (int it = 0; it < 8; ++it) {
      size_t i = base + (size_t)it * 256;
      float4 v = ((const float4*)W_enc)[i];
      half4_t h0;
      h0[0] = (half_t)(v.x * 1024.0f);
      h0[1] = (half_t)(v.y * 1024.0f);
      h0[2] = (half_t)(v.z * 1024.0f);
      h0[3] = (half_t)(v.w * 1024.0f);
      ((half4_t*)W0h)[i] = h0;
    }
    return;
  }
  if (bid < WSPLIT_B + TRANS_B) {
    __shared__ float tile[64][65];
    int t = bid - WSPLIT_B;
    int c0 = (t & 255) * 64;   // over NLAT
    int r0t = (t >> 8) * 64;   // over DMODEL
    int tc = tid & 63, tg = tid >> 6;
    for (int i = 0; i < 16; ++i) {
      int rr = i * 4 + tg;
      tile[rr][tc] = Wd[(size_t)(r0t + rr) * NLAT + c0 + tc];
    }
    __syncthreads();
    for (int i = 0; i < 16; ++i) {
      int cc = i * 4 + tg;
      WdT[(size_t)(c0 + cc) * DMODEL + r0t + tc] = (half_t)tile[tc][cc];
    }
    return;
  }
  int rl = bid - WSPLIT_B - TRANS_B;
  int rg = r0 + rl;
  const float4* px = (const float4*)(x + (size_t)rg * DMODEL);
  float4 v = px[tid];
  double s  = (double)v.x + (double)v.y + (double)v.z + (double)v.w;
  double sq = (double)v.x * v.x + (double)v.y * v.y +
              (double)v.z * v.z + (double)v.w * v.w;
  for (int off = 32; off; off >>= 1) {
    s += __shfl_down(s, off);
    sq += __shfl_down(sq, off);
  }
  __shared__ double ss[4], ssq[4];
  __shared__ double sMean, sNorm;
  int wv = tid >> 6, ln = tid & 63;
  if (ln == 0) { ss[wv] = s; ssq[wv] = sq; }
  __syncthreads();
  if (tid == 0) {
    double S = ss[0] + ss[1] + ss[2] + ss[3];
    double Q = ssq[0] + ssq[1] + ssq[2] + ssq[3];
    double mean = S / (double)DMODEL;
    double var = (Q - (double)DMODEL * mean * mean) / (double)(DMODEL - 1);
    double nrm = sqrt(var) + 1e-6;
    sMean = mean; sNorm = nrm;
    meanD[rg] = mean; normD[rg] = nrm;
  }
  __syncthreads();
  float mean = (float)sMean, nrm = (float)sNorm;
  const float4* pb = (const float4*)b_pre;
  float4 bp = pb[tid];
  float c[4];
  c[0] = ((v.x - mean) / nrm - bp.x) * 1024.0f;
  c[1] = ((v.y - mean) / nrm - bp.y) * 1024.0f;
  c[2] = ((v.z - mean) / nrm - bp.z) * 1024.0f;
  c[3] = ((v.w - mean) / nrm - bp.w) * 1024.0f;
  half4_t h0;
  for (int i = 0; i < 4; ++i) h0[i] = (half_t)c[i];
  ((half4_t*)(X0 + (size_t)rl * DMODEL))[tid] = h0;
}

// ---------------- kernel 2: encode GEMM, 8-phase + one-phase-ahead LDS prefetch ----------------
__global__ __launch_bounds__(512, 2) void gemm_enc(
    const half_t* __restrict__ X0, const half_t* __restrict__ W0,
    const float* __restrict__ b_enc, half_t* __restrict__ h, int mtiles) {
  __shared__ __align__(16) half_t As[2][256 * 64];
  __shared__ __align__(16) half_t Bs[2][256 * 64];
  int tid = threadIdx.x;
  int lane = tid & 63, wave = tid >> 6;
  int wm = wave >> 2, wn = wave & 3;

  int bid = blockIdx.x;
  int xcd = bid & 7, q = bid >> 3;
  int bn = xcd * 8 + (q & 7);
  int bm = q >> 3;
  (void)mtiles;

  const char* Ag = (const char*)(X0 + (size_t)bm * 256 * DMODEL);
  const char* Bg = (const char*)(W0 + (size_t)bn * 256 * DMODEL);

  int srcSwz = ((lane & 7) ^ (lane >> 3)) << 4;
  int rowBase = wave * 8 + (lane >> 3);
  int ldsWOff = wave * 1024;

#define STG_A(b, kt, pr) { int colB = ((kt) & 15) * 128 + srcSwz;             \
    gload16(Ag + (size_t)((pr) * 64 + rowBase) * 2048 + colB,                 \
            (char*)As[b] + (pr) * 8192 + ldsWOff);                            \
    gload16(Ag + (size_t)(((pr) + 2) * 64 + rowBase) * 2048 + colB,           \
            (char*)As[b] + ((pr) + 2) * 8192 + ldsWOff); }
#define STG_B(b, kt, pr) { int colB = ((kt) & 15) * 128 + srcSwz;             \
    gload16(Bg + (size_t)((pr) * 64 + rowBase) * 2048 + colB,                 \
            (char*)Bs[b] + (pr) * 8192 + ldsWOff);                            \
    gload16(Bg + (size_t)(((pr) + 2) * 64 + rowBase) * 2048 + colB,           \
            (char*)Bs[b] + ((pr) + 2) * 8192 + ldsWOff); }

  floatx4 acc[8][4] = {};

  // prologue: tile0 complete + tile1 minus Ap1
  STG_B(0, 0, 0); STG_B(0, 0, 1); STG_A(0, 0, 0); STG_A(0, 0, 1);
  STG_B(1, 1, 0); STG_B(1, 1, 1); STG_A(1, 1, 0);
  asm volatile("s_waitcnt vmcnt(6)" ::: "memory");
  __builtin_amdgcn_sched_barrier(0);
  __builtin_amdgcn_s_barrier();

  int laneQ = (lane & 15) * 128 + (lane >> 4) * 16;
  int sxor = (lane & 7) << 4;
  int aRow = wm * 128 * 128;
  int bRow = wn * 64 * 128;

  half8_t bfr[2][4], afA[4], afB[4];
  const char *Ab, *Bb;

#define LD_B(kk) _Pragma("unroll") for (int t = 0; t < 4; ++t)                \
    bfr[kk][t] = *(const half8_t*)(Bb + ((bRow + t * 2048 +                   \
                                          (kk) * 64 + laneQ) ^ sxor));
#define LD_AF(DST, mh, kk) _Pragma("unroll") for (int t = 0; t < 4; ++t)      \
    DST[t] = *(const half8_t*)(Ab + ((aRow + ((mh) * 4 + t) * 2048 +          \
                                      (kk) * 64 + laneQ) ^ sxor));
#define MM(mb, FR, kk) __builtin_amdgcn_s_setprio(1);                         \
    _Pragma("unroll") for (int mi = 0; mi < 4; ++mi)                          \
    _Pragma("unroll") for (int ni = 0; ni < 4; ++ni)                          \
      acc[(mb) + mi][ni] = __builtin_amdgcn_mfma_f32_16x16x32_f16(            \
          FR[mi], bfr[kk][ni], acc[(mb) + mi][ni], 0, 0, 0);                  \
    __builtin_amdgcn_s_setprio(0);
#define BAR() __builtin_amdgcn_s_barrier()
#define LGKM(n) { asm volatile("s_waitcnt lgkmcnt(" #n ")" ::: "memory");     \
    __builtin_amdgcn_sched_barrier(0); }
#define VM6() { asm volatile("s_waitcnt vmcnt(6)" ::: "memory");              \
    __builtin_amdgcn_sched_barrier(0); }
#define VM0() { asm volatile("s_waitcnt vmcnt(0)" ::: "memory");              \
    __builtin_amdgcn_sched_barrier(0); }

#pragma unroll 1
  for (int i = 0; i < 7; ++i) {
    int t0 = 2 * i;
    // ---- phases 1-4: tile t0 (buf0) ----
    Ab = (const char*)As[0]; Bb = (const char*)Bs[0];
    LD_B(0); LD_B(1); LD_AF(afA, 0, 0); LD_AF(afB, 1, 0);
    STG_A(1, t0 + 1, 1);
    BAR(); LGKM(4); MM(0, afA, 0); BAR();
    LD_AF(afA, 0, 1);
    STG_B(0, t0 + 2, 0);
    BAR(); LGKM(4); MM(4, afB, 0); BAR();
    LD_AF(afB, 1, 1);
    STG_B(0, t0 + 2, 1);
    BAR(); LGKM(4); MM(0, afA, 1); BAR();
    STG_A(0, t0 + 2, 0);
    BAR(); LGKM(0); MM(4, afB, 1); VM6(); BAR();
    // ---- phases 5-8: tile t0+1 (buf1) ----
    Ab = (const char*)As[1]; Bb = (const char*)Bs[1];
    LD_B(0); LD_B(1); LD_AF(afA, 0, 0); LD_AF(afB, 1, 0);
    STG_A(0, t0 + 2, 1);
    BAR(); LGKM(4); MM(0, afA, 0); BAR();
    LD_AF(afA, 0, 1);
    STG_B(1, t0 + 3, 0);
    BAR(); LGKM(4); MM(4, afB, 0); BAR();
    LD_AF(afB, 1, 1);
    STG_B(1, t0 + 3, 1);
    BAR(); LGKM(4); MM(0, afA, 1); BAR();
    STG_A(1, t0 + 3, 0);
    BAR(); LGKM(0); MM(4, afB, 1); VM6(); BAR();
  }
  // ---- peeled i=7 ----
  {
    Ab = (const char*)As[0]; Bb = (const char*)Bs[0];
    LD_B(0); LD_B(1); LD_AF(afA, 0, 0); LD_AF(afB, 1, 0);
    STG_A(1, 15, 1);
    BAR(); LGKM(4); MM(0, afA, 0); BAR();
    LD_AF(afA, 0, 1);
    BAR(); LGKM(4); MM(4, afB, 0); BAR();
    LD_AF(afB, 1, 1);
    BAR(); LGKM(4); MM(0, afA, 1); BAR();
    BAR(); LGKM(0); MM(4, afB, 1); VM0(); BAR();
    Ab = (const char*)As[1]; Bb = (const char*)Bs[1];
    LD_B(0); LD_B(1); LD_AF(afA, 0, 0); LD_AF(afB, 1, 0);
    LGKM(4); MM(0, afA, 0);
    LD_AF(afA, 0, 1);
    LGKM(4); MM(4, afB, 0);
    LD_AF(afB, 1, 1);
    LGKM(4); MM(0, afA, 1);
    LGKM(0); MM(4, afB, 1);
  }
#undef STG_A
#undef STG_B
#undef LD_B
#undef LD_AF
#undef MM
#undef BAR
#undef LGKM
#undef VM6
#undef VM0

  const float scale = 0x1p-20f;
  int rowb = bm * 256 + wm * 128 + ((lane >> 4) * 4);
  int colb = bn * 256 + wn * 64 + (lane & 15);
  float be[4];
#pragma unroll
  for (int ni = 0; ni < 4; ++ni) be[ni] = b_enc[colb + ni * 16];
#pragma unroll
  for (int mi = 0; mi < 8; ++mi)
#pragma unroll
    for (int ni = 0; ni < 4; ++ni)
#pragma unroll
      for (int r = 0; r < 4; ++r)
        h[(size_t)(rowb + mi * 16 + r) * NLAT + colb + ni * 16] =
            (half_t)(acc[mi][ni][r] * scale + be[ni]);
}

// ---------------- kernel 3: fused postprocessing (chunk-max threshold, no histogram) ----------------
// Threshold: T = 32nd-largest of 256 per-thread maxes (disjoint 64-elem subsets).
// Safety: 32 subsets with max > v32 would give 32 values > v32 (contradiction),
// so T <= v32(stored); collecting stored-h >= T - 0.02 (margin >= 2*max GEMM+fp16
// error ~7e-3) is guaranteed to contain every true top-32 index.
__global__ __launch_bounds__(256) void postproc(
    const half_t* __restrict__ h, const float* __restrict__ x,
    const float* __restrict__ b_pre, const float* __restrict__ W_enc,
    const float* __restrict__ b_enc,
    const double* __restrict__ meanD, const double* __restrict__ normD,
    const half_t* __restrict__ WdT, float* __restrict__ out, int r0) {
  int rl = blockIdx.x, tid = threadIdx.x;
  int rg = r0 + rl;
  int wv = tid >> 6, ln = tid & 63;
  const ushort8_t* ph8 = (const ushort8_t*)(h + (size_t)rl * NLAT);

  __shared__ half_t hrow[NLAT];     // 32KB row copy
  __shared__ float tmax[256];
  __shared__ float sThresh;
  __shared__ int cCount;
  __shared__ int cI[CAND_MAX];
  __shared__ double cV[CAND_MAX];
  __shared__ float sVal[32];
  __shared__ int sIdx[32];

  // fp64 normalized row fragment, register-resident
  double mean = meanD[rg], nrm = normD[rg];
  const float* px = x + (size_t)rg * DMODEL;
  double xr[16];
#pragma unroll
  for (int u = 0; u < 16; ++u)
    xr[u] = ((double)px[ln + u * 64] - mean) / nrm - (double)b_pre[ln + u * 64];

  // ---- phase A: copy row to LDS + per-thread max over 64 disjoint values ----
  if (tid == 0) cCount = 0;
  float m = -3.4e38f;
  for (int i = 0; i < 8; ++i) {
    ushort8_t v = ph8[tid + i * 256];
    ((ushort8_t*)hrow)[tid + i * 256] = v;
#pragma unroll
    for (int e = 0; e < 8; ++e) {
      float f = (float)__builtin_bit_cast(_Float16, (unsigned short)v[e]);
      m = fmaxf(m, f);
    }
  }
  tmax[tid] = m;
  __syncthreads();

  // ---- phase A': T = 32nd-largest per-thread max (lexicographic rank) ----
  {
    int rank = 0;
    for (int o = 0; o < 256; ++o) {
      float vo = tmax[o];
      rank += (vo > m || (vo == m && o < tid)) ? 1 : 0;
    }
    if (rank == 31) sThresh = m - 0.02f;
  }
  __syncthreads();
  float thresh = sThresh;

  // ---- phase B: collect candidate indices from the LDS row ----
  for (int i = 0; i < 8; ++i) {
    ushort8_t v = ((const ushort8_t*)hrow)[tid + i * 256];
#pragma unroll
    for (int e = 0; e < 8; ++e) {
      float f = (float)__builtin_bit_cast(_Float16, (unsigned short)v[e]);
      if (f >= thresh) {
        int slot = atomicAdd(&cCount, 1);
        if (slot < CAND_MAX) cI[slot] = (tid + i * 256) * 8 + e;
      }
    }
  }
  __syncthreads();
  int nc = (cCount < CAND_MAX) ? cCount : CAND_MAX;

  // ---- phase C: exact fp64 dots, 4 candidates per wave, 4-way ILP ----
  for (int c0 = wv * 4; c0 < nc; c0 += 16) {
    const float* wp[4];
#pragma unroll
    for (int qq = 0; qq < 4; ++qq) {
      int c = c0 + qq;
      int j = cI[c < nc ? c : (nc - 1)];
      wp[qq] = W_enc + (size_t)j * DMODEL + ln;
    }
    double a0 = 0.0, a1 = 0.0, a2 = 0.0, a3 = 0.0;
#pragma unroll
    for (int u = 0; u < 16; ++u) {
      float w0 = wp[0][u * 64];
      float w1 = wp[1][u * 64];
      float w2 = wp[2][u * 64];
      float w3 = wp[3][u * 64];
      a0 += xr[u] * (double)w0;
      a1 += xr[u] * (double)w1;
      a2 += xr[u] * (double)w2;
      a3 += xr[u] * (double)w3;
    }
    double accq[4] = {a0, a1, a2, a3};
#pragma unroll
    for (int qq = 0; qq < 4; ++qq) {
      double s = accq[qq];
      for (int off = 32; off; off >>= 1) s += __shfl_down(s, off);
      int c = c0 + qq;
      if (ln == 0 && c < nc) cV[c] = s + (double)b_enc[cI[c]];
    }
  }
  if (tid < 32) { sVal[tid] = 0.0f; sIdx[tid] = 0; }
  __syncthreads();

  // ---- phase D: rank-count exact top-32 (value desc, index asc) ----
  for (int c = tid; c < nc; c += 256) {
    double v = cV[c];
    int ix = cI[c];
    int rank = 0;
    for (int o = 0; o < nc; ++o) {
      double vo = cV[o];
      int io = cI[o];
      rank += (vo > v || (vo == v && io < ix)) ? 1 : 0;
    }
    if (rank < 32) {
      sIdx[rank] = ix;
      sVal[rank] = (float)(v > 0.0 ? v : 0.0);  // relu
    }
  }
  __syncthreads();

  // ---- phase E: sparse decode + denormalize ----
  int d0 = tid * 4;
  float4 accv = {0.f, 0.f, 0.f, 0.f};
#pragma unroll 8
  for (int k = 0; k < 32; ++k) {
    float vk = sVal[k];
    const half4_t wvv = *(const half4_t*)(WdT + (size_t)sIdx[k] * DMODEL + d0);
    accv.x += vk * (float)wvv[0]; accv.y += vk * (float)wvv[1];
    accv.z += vk * (float)wvv[2]; accv.w += vk * (float)wvv[3];
  }
  float4 bp = ((const float4*)b_pre)[tid];
  float nrmf = (float)nrm, mnf = (float)mean;
  float4 o;
  o.x = (accv.x + bp.x) * nrmf + mnf;
  o.y = (accv.y + bp.y) * nrmf + mnf;
  o.z = (accv.z + bp.z) * nrmf + mnf;
  o.w = (accv.w + bp.w) * nrmf + mnf;
  ((float4*)(out + (size_t)rg * DMODEL))[tid] = o;
}

// ---------------- launcher ----------------
extern "C" void kernel_launch(void* const* d_in, const int* in_sizes, int n_in,
                              void* d_out, int out_size, void* d_ws, size_t ws_size,
                              hipStream_t stream) {
  const float* x     = (const float*)d_in[0];
  const float* b_pre = (const float*)d_in[1];
  const float* W_enc = (const float*)d_in[2];
  const float* b_enc = (const float*)d_in[3];
  const float* W_dec = (const float*)d_in[4];
  float* out = (float*)d_out;
  char* ws = (char*)d_ws;

  // pick largest row-batch that fits ws_size (min 256 for 256-row GEMM tiles)
  int rowsB = NROWS;
  while (rowsB > 256) {
    size_t need = oBatch + (size_t)rowsB * BATCH_ROW_BYTES;
    if (need <= ws_size) break;
    rowsB >>= 1;
  }
  if (oBatch + (size_t)rowsB * BATCH_ROW_BYTES > ws_size) return;  // fail soft

  half_t* W0 = (half_t*)(ws + oW0);
  half_t* WdT = (half_t*)(ws + oWdT);
  double* meanD = (double*)(ws + oMeanD);
  double* normD = (double*)(ws + oNormD);
  half_t* X0b  = (half_t*)(ws + oBatch);
  half_t* hb   = X0b + (size_t)rowsB * DMODEL;

  for (int r0 = 0; r0 < NROWS; r0 += rowsB) {
    hipLaunchKernelGGL(prepro_kernel,
                       dim3(WSPLIT_B + TRANS_B + rowsB), dim3(256), 0, stream,
                       x, b_pre, W_enc, W_dec, W0, WdT, X0b, meanD, normD, r0);
    int mtiles = rowsB / 256;
    hipLaunchKernelGGL(gemm_enc, dim3(mtiles * 64), dim3(512), 0, stream,
                       X0b, W0, b_enc, hb, mtiles);
    hipLaunchKernelGGL(postproc, dim3(rowsB), dim3(256), 0, stream,
                       hb, x, b_pre, W_enc, b_enc, meanD, normD, WdT, out, r0);
  }
}